// Round 11
// baseline (238.224 us; speedup 1.0000x reference)
//
#include <hip/hip_runtime.h>

#define N_NODES 20000
#define DEG 16
#define GRAPHS 16
#define NPG 1250

typedef __bf16 bf16x8 __attribute__((ext_vector_type(8)));
typedef float f32x4 __attribute__((ext_vector_type(4)));
#define MFMA16(a, b, c) __builtin_amdgcn_mfma_f32_16x16x32_bf16(a, b, c, 0, 0, 0)

// LDS-only barrier: waits LDS ops, does NOT drain vmcnt — global loads stay in
// flight across the barrier (hipBLASLt-style). Safe when inter-wave data flows
// through ds_write/ds_read only.
__device__ __forceinline__ void ldsbar() {
    __asm__ volatile("s_waitcnt lgkmcnt(0)\n\ts_barrier" ::: "memory");
}

// ---- workspace layout (bf16 element offsets) ----
#define OFF_X1    0            // x1 [20000][128] bf16
#define OFF_P1    2560000      // c1W1 packed: MT=8  KT=1 -> 4096
#define OFF_P2    2564096      // c1W2 packed: MT=8  KT=4 -> 16384
#define OFF_P3    2580480      // c2W1 packed: MT=16 KT=5 -> 40960
#define OFF_P4    2621440      // c2W2 packed: MT=16 KT=8 -> 65536
#define OFF_POOL_BYTES 5373952 // pooled u32[16*256]
#define OFF_RELE  2695176      // relE rows of 8 bf16: row (d*16+e) = {rel0,rel1,rel2,0..}
#define RELZ_ROW  320000       //   row 320000 = zeros (written by pack_weights)

__global__ __launch_bounds__(256) void pack_weights(
    const float* __restrict__ c1W1, const float* __restrict__ c1W2,
    const float* __restrict__ c2W1, const float* __restrict__ c2W2,
    __bf16* __restrict__ p1, __bf16* __restrict__ p2,
    __bf16* __restrict__ p3, __bf16* __restrict__ p4,
    unsigned int* __restrict__ pooled, __bf16* __restrict__ relE)
{
    int t = blockIdx.x * 256 + threadIdx.x;
    if (t < GRAPHS * 256) pooled[t] = 0u;             // flipped(-inf) == 0
    if (t == 0) {                                     // zero row for conv2 kt=4 filler lanes
        bf16x8 z;
        #pragma unroll
        for (int j = 0; j < 8; j++) z[j] = (__bf16)0.f;
        *(bf16x8*)&relE[(size_t)RELZ_ROW * 8] = z;
    }
    if (t >= 15872) return;
    const float* W; __bf16* out; int M, Kreal, KT, grp;
    if      (t <  512)  { W = c1W1; out = p1; M = 128; Kreal =   6; KT = 1; grp = t; }
    else if (t < 2560)  { W = c1W2; out = p2; M = 128; Kreal = 128; KT = 4; grp = t - 512; }
    else if (t < 7680)  { W = c2W1; out = p3; M = 256; Kreal = 131; KT = 5; grp = t - 2560; }
    else                { W = c2W2; out = p4; M = 256; Kreal = 256; KT = 8; grp = t - 7680; }
    int lane = grp & 63, rest = grp >> 6;
    int kt = rest % KT, mt = rest / KT;
    int m = mt * 16 + (lane & 15);
    int kbase = kt * 32 + ((lane >> 4) << 3);
    bf16x8 v;
    #pragma unroll
    for (int j = 0; j < 8; j++) {
        int k = kbase + j;
        v[j] = (k < Kreal) ? (__bf16)W[k * M + m] : (__bf16)0.f;
    }
    *(bf16x8*)&out[grp * 8] = v;
}

// =================== conv1 =================== (R9 structure, lds-only barriers)
#define NB1 16
__global__ __launch_bounds__(256, 2) void conv1_kernel(
    const float* __restrict__ pos, const int* __restrict__ esrc,
    const __bf16* __restrict__ W1p, const float* __restrict__ b1,
    const __bf16* __restrict__ W2p, const float* __restrict__ b2,
    __bf16* __restrict__ x1, __bf16* __restrict__ relE)
{
    __shared__ __attribute__((aligned(16))) __bf16 msgF[NB1][16][8];        // 4 KB
    __shared__ __attribute__((aligned(16))) __bf16 hidF[NB1 * 4 * 64 * 8];  // 64 KB
    const int tid = threadIdx.x, lane = tid & 63, wave = tid >> 6;
    const int quad = lane >> 4, col = lane & 15;
    const int node0 = blockIdx.x * NB1;

    bf16x8 A1[2], B2w[2][4];
    f32x4 bias1[2];
    float b2v[2];
    #pragma unroll
    for (int i = 0; i < 2; i++) {
        int mtg = wave * 2 + i;
        A1[i] = *(const bf16x8*)&W1p[(mtg * 64 + lane) * 8];
        bias1[i] = *(const f32x4*)&b1[mtg * 16 + quad * 4];
        #pragma unroll
        for (int kt = 0; kt < 4; kt++)
            B2w[i][kt] = *(const bf16x8*)&W2p[((mtg * 4 + kt) * 64 + lane) * 8];
        b2v[i] = b2[mtg * 16 + col];
    }

    {   // phase 0: fully-parallel gather, one edge per thread
        int nl = tid >> 4, e = tid & 15;
        int d = node0 + nl;
        int s = esrc[d * 16 + e];
        float sx = pos[3*s], sy = pos[3*s+1], sz = pos[3*s+2];
        float dx = pos[3*d], dy = pos[3*d+1], dz = pos[3*d+2];
        __bf16 rx = (__bf16)(sx - dx), ry = (__bf16)(sy - dy), rz = (__bf16)(sz - dz);
        bf16x8 v;
        v[0] = (__bf16)sx; v[1] = (__bf16)sy; v[2] = (__bf16)sz;
        v[3] = rx; v[4] = ry; v[5] = rz;
        v[6] = (__bf16)0.f; v[7] = (__bf16)0.f;
        *(bf16x8*)&msgF[nl][e][0] = v;
        bf16x8 rv;
        rv[0] = rx; rv[1] = ry; rv[2] = rz;
        #pragma unroll
        for (int j = 3; j < 8; j++) rv[j] = (__bf16)0.f;
        *(bf16x8*)&relE[((size_t)d * 16 + e) * 8] = rv;   // conv2 staging source
    }
    ldsbar();

    // phase 1: layer1 MFMA, write hid frags
    #pragma unroll
    for (int nl = 0; nl < NB1; nl++) {
        bf16x8 B;
        if (quad == 0) {
            B = *(const bf16x8*)&msgF[nl][col][0];
        } else {
            #pragma unroll
            for (int j = 0; j < 8; j++) B[j] = (__bf16)0.f;
        }
        #pragma unroll
        for (int i = 0; i < 2; i++) {
            int mtg = wave * 2 + i;
            f32x4 acc = bias1[i];
            acc = MFMA16(A1[i], B, acc);
            union { __bf16 h[4]; uint2 u; } pk;
            #pragma unroll
            for (int r = 0; r < 4; r++) pk.h[r] = (__bf16)fmaxf(acc[r], 0.f);
            int kt2 = mtg >> 1;
            int lane2 = ((mtg * 2 + (quad >> 1)) & 3) * 16 + col;
            int j0 = (quad & 1) * 4;
            *(uint2*)&hidF[((nl * 4 + kt2) * 64 + lane2) * 8 + j0] = pk.u;
        }
    }
    ldsbar();

    // phase 2: D[edge][ch], edge-max, write x1
    #pragma unroll
    for (int nl = 0; nl < NB1; nl++) {
        bf16x8 hA[4];
        #pragma unroll
        for (int kt = 0; kt < 4; kt++)
            hA[kt] = *(const bf16x8*)&hidF[((nl * 4 + kt) * 64 + lane) * 8];
        f32x4 acc[2];
        f32x4 z = {0.f, 0.f, 0.f, 0.f};
        acc[0] = z; acc[1] = z;
        #pragma unroll
        for (int kt = 0; kt < 4; kt++) {
            #pragma unroll
            for (int i = 0; i < 2; i++) acc[i] = MFMA16(hA[kt], B2w[i][kt], acc[i]);
        }
        #pragma unroll
        for (int i = 0; i < 2; i++) {
            int mtg = wave * 2 + i;
            float m = fmaxf(fmaxf(acc[i][0], acc[i][1]), fmaxf(acc[i][2], acc[i][3]));
            m = fmaxf(m, __shfl_xor(m, 16));
            m = fmaxf(m, __shfl_xor(m, 32));
            if (lane < 16)
                x1[(size_t)(node0 + nl) * 128 + mtg * 16 + lane] = (__bf16)(m + b2v[i]);
        }
    }
}

// =================== conv2 ===================
// 500 blocks x 512 threads x 40 nodes (NT2=20 tiles of NB2=2). Specialized:
// waves 0-3 producers (A1 resident; B-frags gathered to REGISTERS, 2-tile
// ping-pong), waves 4-7 consumers (W2 resident, hidF -> layer2 + max-pool).
// NO msgF: the only inter-wave LDS is hidF (ds_write), so ALL barriers are
// lgkmcnt-only (ldsbar) — global gathers stay in flight across barriers,
// eliminating the per-tile vmcnt(0) drain that capped R10 at ~4.6k cyc/tile.
#define NB2 2
#define NT2 20
__global__ __launch_bounds__(512) __attribute__((amdgpu_waves_per_eu(2, 2)))
void conv2_kernel(
    const int* __restrict__ esrc,
    const __bf16* __restrict__ x1, const __bf16* __restrict__ relE,
    const __bf16* __restrict__ W1p, const float* __restrict__ b1,
    const __bf16* __restrict__ W2p, const float* __restrict__ b2,
    unsigned int* __restrict__ pooled)
{
    __shared__ __attribute__((aligned(16))) __bf16 hidF[2][NB2 * 8 * 64 * 8];  // 2x16 KB
    const int tid = threadIdx.x, lane = tid & 63, wave = tid >> 6;
    const int quad = lane >> 4, col = lane & 15;
    const int base = blockIdx.x * (NB2 * NT2);

    if (wave < 4) {
        // ===== producer: layer 1, register-staged B =====
        bf16x8 A1[4][5];
        f32x4 bias1[4];
        #pragma unroll
        for (int i = 0; i < 4; i++) {
            int tg = wave * 4 + i;
            #pragma unroll
            for (int kt = 0; kt < 5; kt++)
                A1[i][kt] = *(const bf16x8*)&W1p[((tg * 5 + kt) * 64 + lane) * 8];
            bias1[i] = *(const f32x4*)&b1[tg * 16 + quad * 4];
        }

        bf16x8 Bc[NB2][5], Bn[NB2][5];
        int sA[NB2], sB[NB2];

        auto loadsrc = [&](int tk, int* s) {
            if (tk >= NT2) return;
            int d0 = base + tk * NB2;
            s[0] = esrc[d0 * 16 + col];
            s[1] = esrc[d0 * 16 + 16 + col];
        };
        auto gather = [&](int tk, const int* s, bf16x8 (&B)[NB2][5]) {
            if (tk >= NT2) return;
            #pragma unroll
            for (int nl = 0; nl < NB2; nl++) {
                #pragma unroll
                for (int kt = 0; kt < 4; kt++)
                    B[nl][kt] = *(const bf16x8*)&x1[(size_t)s[nl] * 128 + kt * 32 + quad * 8];
                int row = (quad == 0) ? ((base + tk * NB2 + nl) * 16 + col) : RELZ_ROW;
                B[nl][4] = *(const bf16x8*)&relE[(size_t)row * 8];
            }
        };
        auto compute = [&](int k, bf16x8 (&B)[NB2][5]) {
            int buf = k & 1;
            #pragma unroll
            for (int nl = 0; nl < NB2; nl++) {
                #pragma unroll
                for (int i = 0; i < 4; i++) {
                    int mtg = wave * 4 + i;
                    f32x4 acc = bias1[i];
                    #pragma unroll
                    for (int kt = 0; kt < 5; kt++) acc = MFMA16(A1[i][kt], B[nl][kt], acc);
                    union { __bf16 h[4]; uint2 u; } pk;
                    #pragma unroll
                    for (int r = 0; r < 4; r++) pk.h[r] = (__bf16)fmaxf(acc[r], 0.f);
                    int kt2 = mtg >> 1;
                    int lane2 = ((mtg * 2 + (quad >> 1)) & 3) * 16 + col;
                    int j0 = (quad & 1) * 4;
                    *(uint2*)&hidF[buf][((nl * 8 + kt2) * 64 + lane2) * 8 + j0] = pk.u;
                }
            }
        };

        loadsrc(0, sA);
        gather(0, sA, Bc);
        loadsrc(1, sB);
        for (int k = 0; k < NT2; k += 2) {
            gather(k + 1, sB, Bn);       // loads in flight across barriers
            loadsrc(k + 2, sA);
            compute(k, Bc);
            ldsbar();                    // hidF[k&1] ready; vmcnt NOT drained
            gather(k + 2, sA, Bc);
            loadsrc(k + 3, sB);
            compute(k + 1, Bn);
            ldsbar();
        }
    } else {
        // ===== consumer: layer 2 + fused global max-pool =====
        const int wv = wave - 4;
        bf16x8 B2r[4][8];
        #pragma unroll
        for (int i = 0; i < 4; i++) {
            int tg = wv * 4 + i;
            #pragma unroll
            for (int kt = 0; kt < 8; kt++)
                B2r[i][kt] = *(const bf16x8*)&W2p[((tg * 8 + kt) * 64 + lane) * 8];
        }
        f32x4 runmax[4];
        #pragma unroll
        for (int i = 0; i < 4; i++)
            #pragma unroll
            for (int r = 0; r < 4; r++) runmax[i][r] = -3.4e38f;
        int gprev = base / NPG;

        auto flushfn = [&]() {
            #pragma unroll
            for (int i = 0; i < 4; i++) {
                float v = fmaxf(fmaxf(runmax[i][0], runmax[i][1]),
                                fmaxf(runmax[i][2], runmax[i][3]));
                v = fmaxf(v, __shfl_xor(v, 16));
                v = fmaxf(v, __shfl_xor(v, 32));
                if (lane < 16) {
                    int c = (wv * 4 + i) * 16 + lane;
                    float val = v + b2[c];
                    unsigned u = __float_as_uint(val);
                    u = (u & 0x80000000u) ? ~u : (u | 0x80000000u);
                    atomicMax(&pooled[gprev * 256 + c], u);
                }
                #pragma unroll
                for (int r = 0; r < 4; r++) runmax[i][r] = -3.4e38f;
            }
        };
        auto consume = [&](int tk) {
            int buf1 = tk & 1;
            int n0 = base + tk * NB2;
            #pragma unroll
            for (int nl = 0; nl < NB2; nl++) {
                int g = (n0 + nl) / NPG;
                if (g != gprev) { flushfn(); gprev = g; }
                bf16x8 hA[8];
                #pragma unroll
                for (int kt = 0; kt < 8; kt++)
                    hA[kt] = *(const bf16x8*)&hidF[buf1][((nl * 8 + kt) * 64 + lane) * 8];
                f32x4 acc[4];
                f32x4 z = {0.f, 0.f, 0.f, 0.f};
                #pragma unroll
                for (int i = 0; i < 4; i++) acc[i] = z;
                #pragma unroll
                for (int kt = 0; kt < 8; kt++) {
                    #pragma unroll
                    for (int i = 0; i < 4; i++) acc[i] = MFMA16(hA[kt], B2r[i][kt], acc[i]);
                }
                #pragma unroll
                for (int i = 0; i < 4; i++)
                    #pragma unroll
                    for (int r = 0; r < 4; r++)
                        runmax[i][r] = fmaxf(runmax[i][r], acc[i][r]);
            }
        };

        for (int k = 0; k < NT2; k++) {
            ldsbar();                    // wait hidF[k&1] ready
            consume(k);
        }
        flushfn();
    }
}

// =================== head (tiny, fp32) ===================
__global__ __launch_bounds__(256) void head_kernel(
    const unsigned int* __restrict__ pooled,
    const float* __restrict__ fc1_W, const float* __restrict__ fc1_b,
    const float* __restrict__ fc2_W, const float* __restrict__ fc2_b,
    const float* __restrict__ lab_W, const float* __restrict__ lab_b,
    const float* __restrict__ box_W, const float* __restrict__ box_b,
    float* __restrict__ out)
{
    __shared__ float p [GRAPHS][256];
    __shared__ float h1[GRAPHS][256];
    __shared__ float h2[GRAPHS][128];
    const int c = threadIdx.x;

    #pragma unroll
    for (int g = 0; g < GRAPHS; g++) {
        unsigned u = pooled[g*256 + c];
        u = (u & 0x80000000u) ? (u & 0x7fffffffu) : ~u;
        p[g][c] = __uint_as_float(u);
    }
    __syncthreads();

    float acc[GRAPHS];
    float bb = fc1_b[c];
    #pragma unroll
    for (int g = 0; g < GRAPHS; g++) acc[g] = bb;
    for (int k = 0; k < 256; k++) {
        float w = fc1_W[k*256 + c];
        #pragma unroll
        for (int g = 0; g < GRAPHS; g++) acc[g] += p[g][k] * w;
    }
    #pragma unroll
    for (int g = 0; g < GRAPHS; g++) h1[g][c] = fmaxf(acc[g], 0.0f);
    __syncthreads();

    if (c < 128) {
        float bb2 = fc2_b[c];
        #pragma unroll
        for (int g = 0; g < GRAPHS; g++) acc[g] = bb2;
        for (int k = 0; k < 256; k++) {
            float w = fc2_W[k*128 + c];
            #pragma unroll
            for (int g = 0; g < GRAPHS; g++) acc[g] += h1[g][k] * w;
        }
        #pragma unroll
        for (int g = 0; g < GRAPHS; g++) h2[g][c] = fmaxf(acc[g], 0.0f);
    }
    __syncthreads();

    if (c < 160) {
        int g = c / 10, j = c % 10;
        float a = lab_b[j];
        for (int k = 0; k < 128; k++) a += h2[g][k] * lab_W[k*10 + j];
        out[c] = a;
    } else {
        int t = c - 160;
        int g = t / 6, j = t % 6;
        float a = box_b[j];
        for (int k = 0; k < 128; k++) a += h2[g][k] * box_W[k*6 + j];
        out[160 + t] = a;
    }
}

extern "C" void kernel_launch(void* const* d_in, const int* in_sizes, int n_in,
                              void* d_out, int out_size, void* d_ws, size_t ws_size,
                              hipStream_t stream) {
    const float* pos   = (const float*)d_in[0];
    const int*   esrc  = (const int*)  d_in[1];
    const float* c1W1 = (const float*)d_in[4];
    const float* c1b1 = (const float*)d_in[5];
    const float* c1W2 = (const float*)d_in[6];
    const float* c1b2 = (const float*)d_in[7];
    const float* c2W1 = (const float*)d_in[8];
    const float* c2b1 = (const float*)d_in[9];
    const float* c2W2 = (const float*)d_in[10];
    const float* c2b2 = (const float*)d_in[11];
    const float* fc1W = (const float*)d_in[12];
    const float* fc1b = (const float*)d_in[13];
    const float* fc2W = (const float*)d_in[14];
    const float* fc2b = (const float*)d_in[15];
    const float* labW = (const float*)d_in[16];
    const float* labb = (const float*)d_in[17];
    const float* boxW = (const float*)d_in[18];
    const float* boxb = (const float*)d_in[19];

    __bf16* wsb = (__bf16*)d_ws;
    __bf16* x1   = wsb + OFF_X1;
    __bf16* p1   = wsb + OFF_P1;
    __bf16* p2   = wsb + OFF_P2;
    __bf16* p3   = wsb + OFF_P3;
    __bf16* p4   = wsb + OFF_P4;
    __bf16* relE = wsb + OFF_RELE;
    unsigned int* pooled = (unsigned int*)((char*)d_ws + OFF_POOL_BYTES);

    pack_weights<<<62, 256, 0, stream>>>(c1W1, c1W2, c2W1, c2W2, p1, p2, p3, p4, pooled, relE);
    conv1_kernel<<<N_NODES / NB1, 256, 0, stream>>>(pos, esrc, p1, c1b1, p2, c1b2, x1, relE);
    conv2_kernel<<<N_NODES / (NB2 * NT2), 512, 0, stream>>>(esrc, x1, relE, p3, c2b1, p4, c2b2, pooled);
    head_kernel<<<1, 256, 0, stream>>>(pooled, fc1W, fc1b, fc2W, fc2b,
                                       labW, labb, boxW, boxb, (float*)d_out);
}

// Round 12
// 232.641 us; speedup vs baseline: 1.0240x; 1.0240x over previous
//
#include <hip/hip_runtime.h>

#define N_NODES 20000
#define DEG 16
#define GRAPHS 16
#define NPG 1250

typedef __bf16 bf16x8 __attribute__((ext_vector_type(8)));
typedef float f32x4 __attribute__((ext_vector_type(4)));
#define MFMA16(a, b, c) __builtin_amdgcn_mfma_f32_16x16x32_bf16(a, b, c, 0, 0, 0)

// LDS-only barrier: waits LDS ops, does NOT drain vmcnt.
__device__ __forceinline__ void ldsbar() {
    __asm__ volatile("s_waitcnt lgkmcnt(0)\n\ts_barrier" ::: "memory");
}
// async global->LDS direct copy, 16 B per lane; LDS dest = uniform base + lane*16
__device__ __forceinline__ void async16(void* lds, const void* g) {
    __builtin_amdgcn_global_load_lds(
        (const __attribute__((address_space(1))) unsigned int*)(g),
        (__attribute__((address_space(3))) unsigned int*)(lds), 16, 0, 0);
}

// ---- workspace layout (bf16 element offsets) ----
#define OFF_X1    0            // x1 [20000][128] bf16
#define OFF_P1    2560000      // c1W1 packed: MT=8  KT=1 -> 4096
#define OFF_P2    2564096      // c1W2 packed: MT=8  KT=4 -> 16384
#define OFF_P3    2580480      // c2W1 packed: MT=16 KT=5 -> 40960
#define OFF_P4    2621440      // c2W2 packed: MT=16 KT=8 -> 65536
#define OFF_POOL_BYTES 5373952 // pooled u32[16*256]
#define OFF_RELE  2695176      // relE rows of 8 bf16: row (d*16+e) = {rel0,rel1,rel2,0..}
#define RELZ_ROW  320000       //   row 320000 = zeros (written by pack_weights)

__global__ __launch_bounds__(256) void pack_weights(
    const float* __restrict__ c1W1, const float* __restrict__ c1W2,
    const float* __restrict__ c2W1, const float* __restrict__ c2W2,
    __bf16* __restrict__ p1, __bf16* __restrict__ p2,
    __bf16* __restrict__ p3, __bf16* __restrict__ p4,
    unsigned int* __restrict__ pooled, __bf16* __restrict__ relE)
{
    int t = blockIdx.x * 256 + threadIdx.x;
    if (t < GRAPHS * 256) pooled[t] = 0u;             // flipped(-inf) == 0
    if (t == 0) {
        bf16x8 z;
        #pragma unroll
        for (int j = 0; j < 8; j++) z[j] = (__bf16)0.f;
        *(bf16x8*)&relE[(size_t)RELZ_ROW * 8] = z;
    }
    if (t >= 15872) return;
    const float* W; __bf16* out; int M, Kreal, KT, grp;
    if      (t <  512)  { W = c1W1; out = p1; M = 128; Kreal =   6; KT = 1; grp = t; }
    else if (t < 2560)  { W = c1W2; out = p2; M = 128; Kreal = 128; KT = 4; grp = t - 512; }
    else if (t < 7680)  { W = c2W1; out = p3; M = 256; Kreal = 131; KT = 5; grp = t - 2560; }
    else                { W = c2W2; out = p4; M = 256; Kreal = 256; KT = 8; grp = t - 7680; }
    int lane = grp & 63, rest = grp >> 6;
    int kt = rest % KT, mt = rest / KT;
    int m = mt * 16 + (lane & 15);
    int kbase = kt * 32 + ((lane >> 4) << 3);
    bf16x8 v;
    #pragma unroll
    for (int j = 0; j < 8; j++) {
        int k = kbase + j;
        v[j] = (k < Kreal) ? (__bf16)W[k * M + m] : (__bf16)0.f;
    }
    *(bf16x8*)&out[grp * 8] = v;
}

// =================== conv1 =================== (R11, unchanged)
#define NB1 16
__global__ __launch_bounds__(256, 2) void conv1_kernel(
    const float* __restrict__ pos, const int* __restrict__ esrc,
    const __bf16* __restrict__ W1p, const float* __restrict__ b1,
    const __bf16* __restrict__ W2p, const float* __restrict__ b2,
    __bf16* __restrict__ x1, __bf16* __restrict__ relE)
{
    __shared__ __attribute__((aligned(16))) __bf16 msgF[NB1][16][8];        // 4 KB
    __shared__ __attribute__((aligned(16))) __bf16 hidF[NB1 * 4 * 64 * 8];  // 64 KB
    const int tid = threadIdx.x, lane = tid & 63, wave = tid >> 6;
    const int quad = lane >> 4, col = lane & 15;
    const int node0 = blockIdx.x * NB1;

    bf16x8 A1[2], B2w[2][4];
    f32x4 bias1[2];
    float b2v[2];
    #pragma unroll
    for (int i = 0; i < 2; i++) {
        int mtg = wave * 2 + i;
        A1[i] = *(const bf16x8*)&W1p[(mtg * 64 + lane) * 8];
        bias1[i] = *(const f32x4*)&b1[mtg * 16 + quad * 4];
        #pragma unroll
        for (int kt = 0; kt < 4; kt++)
            B2w[i][kt] = *(const bf16x8*)&W2p[((mtg * 4 + kt) * 64 + lane) * 8];
        b2v[i] = b2[mtg * 16 + col];
    }

    {   // phase 0: fully-parallel gather, one edge per thread
        int nl = tid >> 4, e = tid & 15;
        int d = node0 + nl;
        int s = esrc[d * 16 + e];
        float sx = pos[3*s], sy = pos[3*s+1], sz = pos[3*s+2];
        float dx = pos[3*d], dy = pos[3*d+1], dz = pos[3*d+2];
        __bf16 rx = (__bf16)(sx - dx), ry = (__bf16)(sy - dy), rz = (__bf16)(sz - dz);
        bf16x8 v;
        v[0] = (__bf16)sx; v[1] = (__bf16)sy; v[2] = (__bf16)sz;
        v[3] = rx; v[4] = ry; v[5] = rz;
        v[6] = (__bf16)0.f; v[7] = (__bf16)0.f;
        *(bf16x8*)&msgF[nl][e][0] = v;
        bf16x8 rv;
        rv[0] = rx; rv[1] = ry; rv[2] = rz;
        #pragma unroll
        for (int j = 3; j < 8; j++) rv[j] = (__bf16)0.f;
        *(bf16x8*)&relE[((size_t)d * 16 + e) * 8] = rv;
    }
    ldsbar();

    #pragma unroll
    for (int nl = 0; nl < NB1; nl++) {
        bf16x8 B;
        if (quad == 0) {
            B = *(const bf16x8*)&msgF[nl][col][0];
        } else {
            #pragma unroll
            for (int j = 0; j < 8; j++) B[j] = (__bf16)0.f;
        }
        #pragma unroll
        for (int i = 0; i < 2; i++) {
            int mtg = wave * 2 + i;
            f32x4 acc = bias1[i];
            acc = MFMA16(A1[i], B, acc);
            union { __bf16 h[4]; uint2 u; } pk;
            #pragma unroll
            for (int r = 0; r < 4; r++) pk.h[r] = (__bf16)fmaxf(acc[r], 0.f);
            int kt2 = mtg >> 1;
            int lane2 = ((mtg * 2 + (quad >> 1)) & 3) * 16 + col;
            int j0 = (quad & 1) * 4;
            *(uint2*)&hidF[((nl * 4 + kt2) * 64 + lane2) * 8 + j0] = pk.u;
        }
    }
    ldsbar();

    #pragma unroll
    for (int nl = 0; nl < NB1; nl++) {
        bf16x8 hA[4];
        #pragma unroll
        for (int kt = 0; kt < 4; kt++)
            hA[kt] = *(const bf16x8*)&hidF[((nl * 4 + kt) * 64 + lane) * 8];
        f32x4 acc[2];
        f32x4 z = {0.f, 0.f, 0.f, 0.f};
        acc[0] = z; acc[1] = z;
        #pragma unroll
        for (int kt = 0; kt < 4; kt++) {
            #pragma unroll
            for (int i = 0; i < 2; i++) acc[i] = MFMA16(hA[kt], B2w[i][kt], acc[i]);
        }
        #pragma unroll
        for (int i = 0; i < 2; i++) {
            int mtg = wave * 2 + i;
            float m = fmaxf(fmaxf(acc[i][0], acc[i][1]), fmaxf(acc[i][2], acc[i][3]));
            m = fmaxf(m, __shfl_xor(m, 16));
            m = fmaxf(m, __shfl_xor(m, 32));
            if (lane < 16)
                x1[(size_t)(node0 + nl) * 128 + mtg * 16 + lane] = (__bf16)(m + b2v[i]);
        }
    }
}

// =================== conv2 ===================
// 500 blocks x 512 thr x 40 nodes (NT2=20 tiles of NB2=2). Producers (waves
// 0-3, A1 resident) / consumers (waves 4-7, W2 resident). msgF TRIPLE-buffered,
// staged by global_load_lds TWO tiles ahead (dummy tail re-stage keeps DMA
// count/tile uniform). All barriers lgkm-only; producers guard msgF reads with
// s_waitcnt vmcnt(6|4) = "all DMAs >=2 periods old done" — never drains the
// in-flight prefetch. Producer steady state has ZERO other vm ops (edge idx
// from LDS sSrc), so the vmcnt depth is exact.
#define NB2 2
#define NT2 20
__global__ __launch_bounds__(512) __attribute__((amdgpu_waves_per_eu(2, 2)))
void conv2_kernel(
    const int* __restrict__ esrc,
    const __bf16* __restrict__ x1, const __bf16* __restrict__ relE,
    const __bf16* __restrict__ W1p, const float* __restrict__ b1,
    const __bf16* __restrict__ W2p, const float* __restrict__ b2,
    unsigned int* __restrict__ pooled)
{
    __shared__ __attribute__((aligned(16))) __bf16 msgF[3][NB2 * 5 * 64 * 8];  // 3x10 KB
    __shared__ __attribute__((aligned(16))) __bf16 hidF[2][NB2 * 8 * 64 * 8];  // 2x16 KB
    __shared__ int sSrc[NB2 * NT2 * 16];                                       // 2.56 KB
    const int tid = threadIdx.x, lane = tid & 63, wave = tid >> 6;
    const int quad = lane >> 4, col = lane & 15;
    const int base = blockIdx.x * (NB2 * NT2);

    for (int u = tid; u < NB2 * NT2 * 16; u += 512) sSrc[u] = esrc[base * 16 + u];
    __syncthreads();

    if (wave < 4) {
        // ===== producer: layer 1 =====
        bf16x8 A1[4][5];
        f32x4 bias1[4];
        #pragma unroll
        for (int i = 0; i < 4; i++) {
            int tg = wave * 4 + i;
            #pragma unroll
            for (int kt = 0; kt < 5; kt++)
                A1[i][kt] = *(const bf16x8*)&W1p[((tg * 5 + kt) * 64 + lane) * 8];
            bias1[i] = *(const f32x4*)&b1[tg * 16 + quad * 4];
        }

        // stage tile td into msgF[buf]; wave handles groups {wave, wave+4, wave+8<10}
        auto stage = [&](int td, int buf) {
            #pragma unroll
            for (int s = 0; s < 3; s++) {
                int g = wave + 4 * s;
                if (g < 10) {
                    int nl = g / 5, kt = g % 5;
                    __bf16* ldst = &msgF[buf][g * 64 * 8];   // + lane*16 implicit
                    const __bf16* gsrc;
                    if (kt < 4) {
                        int src = sSrc[(td * NB2 + nl) * 16 + col];   // ds_read (lgkm)
                        gsrc = &x1[(size_t)src * 128 + kt * 32 + quad * 8];
                    } else {
                        int row = (quad == 0) ? ((base + td * NB2 + nl) * 16 + col) : RELZ_ROW;
                        gsrc = &relE[(size_t)row * 8];
                    }
                    async16(ldst, gsrc);
                }
            }
        };

        stage(0, 0);
        stage(1, 1);

        for (int k = 0; k < NT2; k++) {
            int td = k + 2;                 // dummy re-stage at tail keeps count uniform
            if (td >= NT2) td -= NT2;
            stage(td, (k + 2) % 3);
            // wait only DMAs >= 2 periods old (tiles k+1,k+2 remain in flight)
            if (wave < 2) __asm__ volatile("s_waitcnt vmcnt(6)" ::: "memory");
            else          __asm__ volatile("s_waitcnt vmcnt(4)" ::: "memory");
            // layer1 tile k: msgF[k%3] -> hidF[k&1]
            const int bufi = k % 3, bufo = k & 1;
            #pragma unroll
            for (int nl = 0; nl < NB2; nl++) {
                bf16x8 B[5];
                #pragma unroll
                for (int kt = 0; kt < 5; kt++)
                    B[kt] = *(const bf16x8*)&msgF[bufi][((nl * 5 + kt) * 64 + lane) * 8];
                #pragma unroll
                for (int i = 0; i < 4; i++) {
                    int mtg = wave * 4 + i;
                    f32x4 acc = bias1[i];
                    #pragma unroll
                    for (int kt = 0; kt < 5; kt++) acc = MFMA16(A1[i][kt], B[kt], acc);
                    union { __bf16 h[4]; uint2 u; } pk;
                    #pragma unroll
                    for (int r = 0; r < 4; r++) pk.h[r] = (__bf16)fmaxf(acc[r], 0.f);
                    int kt2 = mtg >> 1;
                    int lane2 = ((mtg * 2 + (quad >> 1)) & 3) * 16 + col;
                    int j0 = (quad & 1) * 4;
                    *(uint2*)&hidF[bufo][((nl * 8 + kt2) * 64 + lane2) * 8 + j0] = pk.u;
                }
            }
            ldsbar();                       // hidF[k] ready; DMAs stay in flight
        }
    } else {
        // ===== consumer: layer 2 + fused global max-pool =====
        const int wv = wave - 4;
        bf16x8 B2r[4][8];
        #pragma unroll
        for (int i = 0; i < 4; i++) {
            int tg = wv * 4 + i;
            #pragma unroll
            for (int kt = 0; kt < 8; kt++)
                B2r[i][kt] = *(const bf16x8*)&W2p[((tg * 8 + kt) * 64 + lane) * 8];
        }
        f32x4 runmax[4];
        #pragma unroll
        for (int i = 0; i < 4; i++)
            #pragma unroll
            for (int r = 0; r < 4; r++) runmax[i][r] = -3.4e38f;
        int gprev = base / NPG;

        auto flushfn = [&]() {
            #pragma unroll
            for (int i = 0; i < 4; i++) {
                float v = fmaxf(fmaxf(runmax[i][0], runmax[i][1]),
                                fmaxf(runmax[i][2], runmax[i][3]));
                v = fmaxf(v, __shfl_xor(v, 16));
                v = fmaxf(v, __shfl_xor(v, 32));
                if (lane < 16) {
                    int c = (wv * 4 + i) * 16 + lane;
                    float val = v + b2[c];
                    unsigned u = __float_as_uint(val);
                    u = (u & 0x80000000u) ? ~u : (u | 0x80000000u);
                    atomicMax(&pooled[gprev * 256 + c], u);
                }
                #pragma unroll
                for (int r = 0; r < 4; r++) runmax[i][r] = -3.4e38f;
            }
        };
        auto consume = [&](int tk) {
            int buf1 = tk & 1;
            int n0 = base + tk * NB2;
            #pragma unroll
            for (int nl = 0; nl < NB2; nl++) {
                int g = (n0 + nl) / NPG;
                if (g != gprev) { flushfn(); gprev = g; }
                bf16x8 hA[8];
                #pragma unroll
                for (int kt = 0; kt < 8; kt++)
                    hA[kt] = *(const bf16x8*)&hidF[buf1][((nl * 8 + kt) * 64 + lane) * 8];
                f32x4 acc[4];
                f32x4 z = {0.f, 0.f, 0.f, 0.f};
                #pragma unroll
                for (int i = 0; i < 4; i++) acc[i] = z;
                #pragma unroll
                for (int kt = 0; kt < 8; kt++) {
                    #pragma unroll
                    for (int i = 0; i < 4; i++) acc[i] = MFMA16(hA[kt], B2r[i][kt], acc[i]);
                }
                #pragma unroll
                for (int i = 0; i < 4; i++)
                    #pragma unroll
                    for (int r = 0; r < 4; r++)
                        runmax[i][r] = fmaxf(runmax[i][r], acc[i][r]);
            }
        };

        for (int k = 0; k < NT2; k++) {
            ldsbar();                       // hidF[k] ready
            consume(k);
        }
        flushfn();
    }
}

// =================== head (tiny, fp32) ===================
__global__ __launch_bounds__(256) void head_kernel(
    const unsigned int* __restrict__ pooled,
    const float* __restrict__ fc1_W, const float* __restrict__ fc1_b,
    const float* __restrict__ fc2_W, const float* __restrict__ fc2_b,
    const float* __restrict__ lab_W, const float* __restrict__ lab_b,
    const float* __restrict__ box_W, const float* __restrict__ box_b,
    float* __restrict__ out)
{
    __shared__ float p [GRAPHS][256];
    __shared__ float h1[GRAPHS][256];
    __shared__ float h2[GRAPHS][128];
    const int c = threadIdx.x;

    #pragma unroll
    for (int g = 0; g < GRAPHS; g++) {
        unsigned u = pooled[g*256 + c];
        u = (u & 0x80000000u) ? (u & 0x7fffffffu) : ~u;
        p[g][c] = __uint_as_float(u);
    }
    __syncthreads();

    float acc[GRAPHS];
    float bb = fc1_b[c];
    #pragma unroll
    for (int g = 0; g < GRAPHS; g++) acc[g] = bb;
    for (int k = 0; k < 256; k++) {
        float w = fc1_W[k*256 + c];
        #pragma unroll
        for (int g = 0; g < GRAPHS; g++) acc[g] += p[g][k] * w;
    }
    #pragma unroll
    for (int g = 0; g < GRAPHS; g++) h1[g][c] = fmaxf(acc[g], 0.0f);
    __syncthreads();

    if (c < 128) {
        float bb2 = fc2_b[c];
        #pragma unroll
        for (int g = 0; g < GRAPHS; g++) acc[g] = bb2;
        for (int k = 0; k < 256; k++) {
            float w = fc2_W[k*128 + c];
            #pragma unroll
            for (int g = 0; g < GRAPHS; g++) acc[g] += h1[g][k] * w;
        }
        #pragma unroll
        for (int g = 0; g < GRAPHS; g++) h2[g][c] = fmaxf(acc[g], 0.0f);
    }
    __syncthreads();

    if (c < 160) {
        int g = c / 10, j = c % 10;
        float a = lab_b[j];
        for (int k = 0; k < 128; k++) a += h2[g][k] * lab_W[k*10 + j];
        out[c] = a;
    } else {
        int t = c - 160;
        int g = t / 6, j = t % 6;
        float a = box_b[j];
        for (int k = 0; k < 128; k++) a += h2[g][k] * box_W[k*6 + j];
        out[160 + t] = a;
    }
}

extern "C" void kernel_launch(void* const* d_in, const int* in_sizes, int n_in,
                              void* d_out, int out_size, void* d_ws, size_t ws_size,
                              hipStream_t stream) {
    const float* pos   = (const float*)d_in[0];
    const int*   esrc  = (const int*)  d_in[1];
    const float* c1W1 = (const float*)d_in[4];
    const float* c1b1 = (const float*)d_in[5];
    const float* c1W2 = (const float*)d_in[6];
    const float* c1b2 = (const float*)d_in[7];
    const float* c2W1 = (const float*)d_in[8];
    const float* c2b1 = (const float*)d_in[9];
    const float* c2W2 = (const float*)d_in[10];
    const float* c2b2 = (const float*)d_in[11];
    const float* fc1W = (const float*)d_in[12];
    const float* fc1b = (const float*)d_in[13];
    const float* fc2W = (const float*)d_in[14];
    const float* fc2b = (const float*)d_in[15];
    const float* labW = (const float*)d_in[16];
    const float* labb = (const float*)d_in[17];
    const float* boxW = (const float*)d_in[18];
    const float* boxb = (const float*)d_in[19];

    __bf16* wsb = (__bf16*)d_ws;
    __bf16* x1   = wsb + OFF_X1;
    __bf16* p1   = wsb + OFF_P1;
    __bf16* p2   = wsb + OFF_P2;
    __bf16* p3   = wsb + OFF_P3;
    __bf16* p4   = wsb + OFF_P4;
    __bf16* relE = wsb + OFF_RELE;
    unsigned int* pooled = (unsigned int*)((char*)d_ws + OFF_POOL_BYTES);

    pack_weights<<<62, 256, 0, stream>>>(c1W1, c1W2, c2W1, c2W2, p1, p2, p3, p4, pooled, relE);
    conv1_kernel<<<N_NODES / NB1, 256, 0, stream>>>(pos, esrc, p1, c1b1, p2, c1b2, x1, relE);
    conv2_kernel<<<N_NODES / (NB2 * NT2), 512, 0, stream>>>(esrc, x1, relE, p3, c2b1, p4, c2b2, pooled);
    head_kernel<<<1, 256, 0, stream>>>(pooled, fc1W, fc1b, fc2W, fc2b,
                                       labW, labb, boxW, boxb, (float*)d_out);
}

// Round 13
// 215.622 us; speedup vs baseline: 1.1048x; 1.0789x over previous
//
#include <hip/hip_runtime.h>

#define N_NODES 20000
#define DEG 16
#define GRAPHS 16
#define NPG 1250

typedef __bf16 bf16x8 __attribute__((ext_vector_type(8)));
typedef float f32x4 __attribute__((ext_vector_type(4)));
#define MFMA16(a, b, c) __builtin_amdgcn_mfma_f32_16x16x32_bf16(a, b, c, 0, 0, 0)

// LDS-only barrier: waits LDS ops, does NOT drain vmcnt.
__device__ __forceinline__ void ldsbar() {
    __asm__ volatile("s_waitcnt lgkmcnt(0)\n\ts_barrier" ::: "memory");
}
// async global->LDS direct copy, 16 B per lane; LDS dest = uniform base + lane*16
__device__ __forceinline__ void async16(void* lds, const void* g) {
    __builtin_amdgcn_global_load_lds(
        (const __attribute__((address_space(1))) unsigned int*)(g),
        (__attribute__((address_space(3))) unsigned int*)(lds), 16, 0, 0);
}

// ---- workspace layout ----
#define OFF_X1    0            // x1 [20000][128] bf16
#define OFF_P1    2560000      // c1W1 packed: MT=8  KT=1 -> 4096
#define OFF_P2    2564096      // c1W2 packed: MT=8  KT=4 -> 16384
#define OFF_P3    2580480      // c2W1 packed: MT=16 KT=5 -> 40960
#define OFF_P4    2621440      // c2W2 packed: MT=16 KT=8 -> 65536
#define OFF_POOL_BYTES 5373952 // pooled u32[16*256] (bytes 5373952..5390336)
#define OFF_RELE  2695176      // relE (bf16 elems): bytes 5390352..10510368
#define RELZ_ROW  320000       //   row 320000 = zeros (written by pack_weights)
#define OFF_H1_BYTES 10510400  // h1 f32[16*256] = 16 KB

__global__ __launch_bounds__(256) void pack_weights(
    const float* __restrict__ c1W1, const float* __restrict__ c1W2,
    const float* __restrict__ c2W1, const float* __restrict__ c2W2,
    __bf16* __restrict__ p1, __bf16* __restrict__ p2,
    __bf16* __restrict__ p3, __bf16* __restrict__ p4,
    unsigned int* __restrict__ pooled, __bf16* __restrict__ relE)
{
    int t = blockIdx.x * 256 + threadIdx.x;
    if (t < GRAPHS * 256) pooled[t] = 0u;             // flipped(-inf) == 0
    if (t == 0) {
        bf16x8 z;
        #pragma unroll
        for (int j = 0; j < 8; j++) z[j] = (__bf16)0.f;
        *(bf16x8*)&relE[(size_t)RELZ_ROW * 8] = z;
    }
    if (t >= 15872) return;
    const float* W; __bf16* out; int M, Kreal, KT, grp;
    if      (t <  512)  { W = c1W1; out = p1; M = 128; Kreal =   6; KT = 1; grp = t; }
    else if (t < 2560)  { W = c1W2; out = p2; M = 128; Kreal = 128; KT = 4; grp = t - 512; }
    else if (t < 7680)  { W = c2W1; out = p3; M = 256; Kreal = 131; KT = 5; grp = t - 2560; }
    else                { W = c2W2; out = p4; M = 256; Kreal = 256; KT = 8; grp = t - 7680; }
    int lane = grp & 63, rest = grp >> 6;
    int kt = rest % KT, mt = rest / KT;
    int m = mt * 16 + (lane & 15);
    int kbase = kt * 32 + ((lane >> 4) << 3);
    bf16x8 v;
    #pragma unroll
    for (int j = 0; j < 8; j++) {
        int k = kbase + j;
        v[j] = (k < Kreal) ? (__bf16)W[k * M + m] : (__bf16)0.f;
    }
    *(bf16x8*)&out[grp * 8] = v;
}

// =================== conv1 =================== (unchanged)
#define NB1 16
__global__ __launch_bounds__(256, 2) void conv1_kernel(
    const float* __restrict__ pos, const int* __restrict__ esrc,
    const __bf16* __restrict__ W1p, const float* __restrict__ b1,
    const __bf16* __restrict__ W2p, const float* __restrict__ b2,
    __bf16* __restrict__ x1, __bf16* __restrict__ relE)
{
    __shared__ __attribute__((aligned(16))) __bf16 msgF[NB1][16][8];        // 4 KB
    __shared__ __attribute__((aligned(16))) __bf16 hidF[NB1 * 4 * 64 * 8];  // 64 KB
    const int tid = threadIdx.x, lane = tid & 63, wave = tid >> 6;
    const int quad = lane >> 4, col = lane & 15;
    const int node0 = blockIdx.x * NB1;

    bf16x8 A1[2], B2w[2][4];
    f32x4 bias1[2];
    float b2v[2];
    #pragma unroll
    for (int i = 0; i < 2; i++) {
        int mtg = wave * 2 + i;
        A1[i] = *(const bf16x8*)&W1p[(mtg * 64 + lane) * 8];
        bias1[i] = *(const f32x4*)&b1[mtg * 16 + quad * 4];
        #pragma unroll
        for (int kt = 0; kt < 4; kt++)
            B2w[i][kt] = *(const bf16x8*)&W2p[((mtg * 4 + kt) * 64 + lane) * 8];
        b2v[i] = b2[mtg * 16 + col];
    }

    {   // phase 0: fully-parallel gather, one edge per thread
        int nl = tid >> 4, e = tid & 15;
        int d = node0 + nl;
        int s = esrc[d * 16 + e];
        float sx = pos[3*s], sy = pos[3*s+1], sz = pos[3*s+2];
        float dx = pos[3*d], dy = pos[3*d+1], dz = pos[3*d+2];
        __bf16 rx = (__bf16)(sx - dx), ry = (__bf16)(sy - dy), rz = (__bf16)(sz - dz);
        bf16x8 v;
        v[0] = (__bf16)sx; v[1] = (__bf16)sy; v[2] = (__bf16)sz;
        v[3] = rx; v[4] = ry; v[5] = rz;
        v[6] = (__bf16)0.f; v[7] = (__bf16)0.f;
        *(bf16x8*)&msgF[nl][e][0] = v;
        bf16x8 rv;
        rv[0] = rx; rv[1] = ry; rv[2] = rz;
        #pragma unroll
        for (int j = 3; j < 8; j++) rv[j] = (__bf16)0.f;
        *(bf16x8*)&relE[((size_t)d * 16 + e) * 8] = rv;
    }
    ldsbar();

    #pragma unroll
    for (int nl = 0; nl < NB1; nl++) {
        bf16x8 B;
        if (quad == 0) {
            B = *(const bf16x8*)&msgF[nl][col][0];
        } else {
            #pragma unroll
            for (int j = 0; j < 8; j++) B[j] = (__bf16)0.f;
        }
        #pragma unroll
        for (int i = 0; i < 2; i++) {
            int mtg = wave * 2 + i;
            f32x4 acc = bias1[i];
            acc = MFMA16(A1[i], B, acc);
            union { __bf16 h[4]; uint2 u; } pk;
            #pragma unroll
            for (int r = 0; r < 4; r++) pk.h[r] = (__bf16)fmaxf(acc[r], 0.f);
            int kt2 = mtg >> 1;
            int lane2 = ((mtg * 2 + (quad >> 1)) & 3) * 16 + col;
            int j0 = (quad & 1) * 4;
            *(uint2*)&hidF[((nl * 4 + kt2) * 64 + lane2) * 8 + j0] = pk.u;
        }
    }
    ldsbar();

    #pragma unroll
    for (int nl = 0; nl < NB1; nl++) {
        bf16x8 hA[4];
        #pragma unroll
        for (int kt = 0; kt < 4; kt++)
            hA[kt] = *(const bf16x8*)&hidF[((nl * 4 + kt) * 64 + lane) * 8];
        f32x4 acc[2];
        f32x4 z = {0.f, 0.f, 0.f, 0.f};
        acc[0] = z; acc[1] = z;
        #pragma unroll
        for (int kt = 0; kt < 4; kt++) {
            #pragma unroll
            for (int i = 0; i < 2; i++) acc[i] = MFMA16(hA[kt], B2w[i][kt], acc[i]);
        }
        #pragma unroll
        for (int i = 0; i < 2; i++) {
            int mtg = wave * 2 + i;
            float m = fmaxf(fmaxf(acc[i][0], acc[i][1]), fmaxf(acc[i][2], acc[i][3]));
            m = fmaxf(m, __shfl_xor(m, 16));
            m = fmaxf(m, __shfl_xor(m, 32));
            if (lane < 16)
                x1[(size_t)(node0 + nl) * 128 + mtg * 16 + lane] = (__bf16)(m + b2v[i]);
        }
    }
}

// =================== conv2 =================== (R12, unchanged)
#define NB2 2
#define NT2 20
__global__ __launch_bounds__(512) __attribute__((amdgpu_waves_per_eu(2, 2)))
void conv2_kernel(
    const int* __restrict__ esrc,
    const __bf16* __restrict__ x1, const __bf16* __restrict__ relE,
    const __bf16* __restrict__ W1p, const float* __restrict__ b1,
    const __bf16* __restrict__ W2p, const float* __restrict__ b2,
    unsigned int* __restrict__ pooled)
{
    __shared__ __attribute__((aligned(16))) __bf16 msgF[3][NB2 * 5 * 64 * 8];  // 3x10 KB
    __shared__ __attribute__((aligned(16))) __bf16 hidF[2][NB2 * 8 * 64 * 8];  // 2x16 KB
    __shared__ int sSrc[NB2 * NT2 * 16];                                       // 2.56 KB
    const int tid = threadIdx.x, lane = tid & 63, wave = tid >> 6;
    const int quad = lane >> 4, col = lane & 15;
    const int base = blockIdx.x * (NB2 * NT2);

    for (int u = tid; u < NB2 * NT2 * 16; u += 512) sSrc[u] = esrc[base * 16 + u];
    __syncthreads();

    if (wave < 4) {
        bf16x8 A1[4][5];
        f32x4 bias1[4];
        #pragma unroll
        for (int i = 0; i < 4; i++) {
            int tg = wave * 4 + i;
            #pragma unroll
            for (int kt = 0; kt < 5; kt++)
                A1[i][kt] = *(const bf16x8*)&W1p[((tg * 5 + kt) * 64 + lane) * 8];
            bias1[i] = *(const f32x4*)&b1[tg * 16 + quad * 4];
        }

        auto stage = [&](int td, int buf) {
            #pragma unroll
            for (int s = 0; s < 3; s++) {
                int g = wave + 4 * s;
                if (g < 10) {
                    int nl = g / 5, kt = g % 5;
                    __bf16* ldst = &msgF[buf][g * 64 * 8];
                    const __bf16* gsrc;
                    if (kt < 4) {
                        int src = sSrc[(td * NB2 + nl) * 16 + col];
                        gsrc = &x1[(size_t)src * 128 + kt * 32 + quad * 8];
                    } else {
                        int row = (quad == 0) ? ((base + td * NB2 + nl) * 16 + col) : RELZ_ROW;
                        gsrc = &relE[(size_t)row * 8];
                    }
                    async16(ldst, gsrc);
                }
            }
        };

        stage(0, 0);
        stage(1, 1);

        for (int k = 0; k < NT2; k++) {
            int td = k + 2;
            if (td >= NT2) td -= NT2;
            stage(td, (k + 2) % 3);
            if (wave < 2) __asm__ volatile("s_waitcnt vmcnt(6)" ::: "memory");
            else          __asm__ volatile("s_waitcnt vmcnt(4)" ::: "memory");
            const int bufi = k % 3, bufo = k & 1;
            #pragma unroll
            for (int nl = 0; nl < NB2; nl++) {
                bf16x8 B[5];
                #pragma unroll
                for (int kt = 0; kt < 5; kt++)
                    B[kt] = *(const bf16x8*)&msgF[bufi][((nl * 5 + kt) * 64 + lane) * 8];
                #pragma unroll
                for (int i = 0; i < 4; i++) {
                    int mtg = wave * 4 + i;
                    f32x4 acc = bias1[i];
                    #pragma unroll
                    for (int kt = 0; kt < 5; kt++) acc = MFMA16(A1[i][kt], B[kt], acc);
                    union { __bf16 h[4]; uint2 u; } pk;
                    #pragma unroll
                    for (int r = 0; r < 4; r++) pk.h[r] = (__bf16)fmaxf(acc[r], 0.f);
                    int kt2 = mtg >> 1;
                    int lane2 = ((mtg * 2 + (quad >> 1)) & 3) * 16 + col;
                    int j0 = (quad & 1) * 4;
                    *(uint2*)&hidF[bufo][((nl * 8 + kt2) * 64 + lane2) * 8 + j0] = pk.u;
                }
            }
            ldsbar();
        }
    } else {
        const int wv = wave - 4;
        bf16x8 B2r[4][8];
        #pragma unroll
        for (int i = 0; i < 4; i++) {
            int tg = wv * 4 + i;
            #pragma unroll
            for (int kt = 0; kt < 8; kt++)
                B2r[i][kt] = *(const bf16x8*)&W2p[((tg * 8 + kt) * 64 + lane) * 8];
        }
        f32x4 runmax[4];
        #pragma unroll
        for (int i = 0; i < 4; i++)
            #pragma unroll
            for (int r = 0; r < 4; r++) runmax[i][r] = -3.4e38f;
        int gprev = base / NPG;

        auto flushfn = [&]() {
            #pragma unroll
            for (int i = 0; i < 4; i++) {
                float v = fmaxf(fmaxf(runmax[i][0], runmax[i][1]),
                                fmaxf(runmax[i][2], runmax[i][3]));
                v = fmaxf(v, __shfl_xor(v, 16));
                v = fmaxf(v, __shfl_xor(v, 32));
                if (lane < 16) {
                    int c = (wv * 4 + i) * 16 + lane;
                    float val = v + b2[c];
                    unsigned u = __float_as_uint(val);
                    u = (u & 0x80000000u) ? ~u : (u | 0x80000000u);
                    atomicMax(&pooled[gprev * 256 + c], u);
                }
                #pragma unroll
                for (int r = 0; r < 4; r++) runmax[i][r] = -3.4e38f;
            }
        };
        auto consume = [&](int tk) {
            int buf1 = tk & 1;
            int n0 = base + tk * NB2;
            #pragma unroll
            for (int nl = 0; nl < NB2; nl++) {
                int g = (n0 + nl) / NPG;
                if (g != gprev) { flushfn(); gprev = g; }
                bf16x8 hA[8];
                #pragma unroll
                for (int kt = 0; kt < 8; kt++)
                    hA[kt] = *(const bf16x8*)&hidF[buf1][((nl * 8 + kt) * 64 + lane) * 8];
                f32x4 acc[4];
                f32x4 z = {0.f, 0.f, 0.f, 0.f};
                #pragma unroll
                for (int i = 0; i < 4; i++) acc[i] = z;
                #pragma unroll
                for (int kt = 0; kt < 8; kt++) {
                    #pragma unroll
                    for (int i = 0; i < 4; i++) acc[i] = MFMA16(hA[kt], B2r[i][kt], acc[i]);
                }
                #pragma unroll
                for (int i = 0; i < 4; i++)
                    #pragma unroll
                    for (int r = 0; r < 4; r++)
                        runmax[i][r] = fmaxf(runmax[i][r], acc[i][r]);
            }
        };

        for (int k = 0; k < NT2; k++) {
            ldsbar();
            consume(k);
        }
        flushfn();
    }
}

// =================== head, stage 1: fc1 (16 blocks, one per graph) ===================
__global__ __launch_bounds__(256) void head1_kernel(
    const unsigned int* __restrict__ pooled,
    const float* __restrict__ fc1_W, const float* __restrict__ fc1_b,
    float* __restrict__ h1)
{
    __shared__ float p[256];
    const int g = blockIdx.x, c = threadIdx.x;
    unsigned u = pooled[g * 256 + c];
    u = (u & 0x80000000u) ? (u & 0x7fffffffu) : ~u;
    p[c] = __uint_as_float(u);
    __syncthreads();
    float acc = fc1_b[c];
    #pragma unroll 8
    for (int k = 0; k < 256; k++) acc += p[k] * fc1_W[k * 256 + c];
    h1[g * 256 + c] = fmaxf(acc, 0.f);
}

// =================== head, stage 2: fc2 + lab + box (16 blocks) ===================
__global__ __launch_bounds__(128) void head2_kernel(
    const float* __restrict__ h1,
    const float* __restrict__ fc2_W, const float* __restrict__ fc2_b,
    const float* __restrict__ lab_W, const float* __restrict__ lab_b,
    const float* __restrict__ box_W, const float* __restrict__ box_b,
    float* __restrict__ out)
{
    __shared__ float hs[256];
    __shared__ float h2s[128];
    const int g = blockIdx.x, c = threadIdx.x;
    hs[c]       = h1[g * 256 + c];
    hs[c + 128] = h1[g * 256 + 128 + c];
    __syncthreads();
    float acc = fc2_b[c];
    #pragma unroll 8
    for (int k = 0; k < 256; k++) acc += hs[k] * fc2_W[k * 128 + c];
    h2s[c] = fmaxf(acc, 0.f);
    __syncthreads();
    if (c < 10) {
        float a = lab_b[c];
        #pragma unroll 8
        for (int k = 0; k < 128; k++) a += h2s[k] * lab_W[k * 10 + c];
        out[g * 10 + c] = a;                       // labels [16][10]
    } else if (c < 16) {
        int j = c - 10;
        float a = box_b[j];
        #pragma unroll 8
        for (int k = 0; k < 128; k++) a += h2s[k] * box_W[k * 6 + j];
        out[160 + g * 6 + j] = a;                  // bbox [16][6]
    }
}

extern "C" void kernel_launch(void* const* d_in, const int* in_sizes, int n_in,
                              void* d_out, int out_size, void* d_ws, size_t ws_size,
                              hipStream_t stream) {
    const float* pos   = (const float*)d_in[0];
    const int*   esrc  = (const int*)  d_in[1];
    const float* c1W1 = (const float*)d_in[4];
    const float* c1b1 = (const float*)d_in[5];
    const float* c1W2 = (const float*)d_in[6];
    const float* c1b2 = (const float*)d_in[7];
    const float* c2W1 = (const float*)d_in[8];
    const float* c2b1 = (const float*)d_in[9];
    const float* c2W2 = (const float*)d_in[10];
    const float* c2b2 = (const float*)d_in[11];
    const float* fc1W = (const float*)d_in[12];
    const float* fc1b = (const float*)d_in[13];
    const float* fc2W = (const float*)d_in[14];
    const float* fc2b = (const float*)d_in[15];
    const float* labW = (const float*)d_in[16];
    const float* labb = (const float*)d_in[17];
    const float* boxW = (const float*)d_in[18];
    const float* boxb = (const float*)d_in[19];

    __bf16* wsb = (__bf16*)d_ws;
    __bf16* x1   = wsb + OFF_X1;
    __bf16* p1   = wsb + OFF_P1;
    __bf16* p2   = wsb + OFF_P2;
    __bf16* p3   = wsb + OFF_P3;
    __bf16* p4   = wsb + OFF_P4;
    __bf16* relE = wsb + OFF_RELE;
    unsigned int* pooled = (unsigned int*)((char*)d_ws + OFF_POOL_BYTES);
    float* h1 = (float*)((char*)d_ws + OFF_H1_BYTES);

    pack_weights<<<62, 256, 0, stream>>>(c1W1, c1W2, c2W1, c2W2, p1, p2, p3, p4, pooled, relE);
    conv1_kernel<<<N_NODES / NB1, 256, 0, stream>>>(pos, esrc, p1, c1b1, p2, c1b2, x1, relE);
    conv2_kernel<<<N_NODES / (NB2 * NT2), 512, 0, stream>>>(esrc, x1, relE, p3, c2b1, p4, c2b2, pooled);
    head1_kernel<<<GRAPHS, 256, 0, stream>>>(pooled, fc1W, fc1b, h1);
    head2_kernel<<<GRAPHS, 128, 0, stream>>>(h1, fc2W, fc2b, labW, labb, boxW, boxb, (float*)d_out);
}

// Round 14
// 192.385 us; speedup vs baseline: 1.2383x; 1.1208x over previous
//
#include <hip/hip_runtime.h>

#define N_NODES 20000
#define DEG 16
#define GRAPHS 16
#define NPG 1250

typedef __bf16 bf16x8 __attribute__((ext_vector_type(8)));
typedef float f32x4 __attribute__((ext_vector_type(4)));
#define MFMA16(a, b, c) __builtin_amdgcn_mfma_f32_16x16x32_bf16(a, b, c, 0, 0, 0)

// LDS-only barrier: waits LDS ops, does NOT drain vmcnt.
__device__ __forceinline__ void ldsbar() {
    __asm__ volatile("s_waitcnt lgkmcnt(0)\n\ts_barrier" ::: "memory");
}
// async global->LDS direct copy, 16 B per lane; LDS dest = uniform base + lane*16
__device__ __forceinline__ void async16(void* lds, const void* g) {
    __builtin_amdgcn_global_load_lds(
        (const __attribute__((address_space(1))) unsigned int*)(g),
        (__attribute__((address_space(3))) unsigned int*)(lds), 16, 0, 0);
}

// ---- workspace layout ----
#define OFF_X1    0            // x1 [20000][128] bf16
#define OFF_P1    2560000      // c1W1 packed: MT=8  KT=1 -> 4096
#define OFF_P2    2564096      // c1W2 packed: MT=8  KT=4 -> 16384
#define OFF_P3    2580480      // c2W1 packed: MT=16 KT=5 -> 40960
#define OFF_P4    2621440      // c2W2 packed: MT=16 KT=8 -> 65536
#define OFF_POOL_BYTES 5373952 // pooled u32[16*256] (bytes 5373952..5390336)
#define OFF_MSGE  2695176      // msgE (bf16 elems): row e = [sx,sy,sz,rx,ry,rz,0,0]
#define ZROW      320000       //   row 320000 = zeros (written by pack_weights)

// Frag layout (A-role == B-role for mfma_f32_16x16x32_bf16):
//   frag[((t*KT+kt)*64+lane)*8 + j] = X[k = kt*32 + (lane>>4)*8 + j][idx = lane&15]
// c2W1 (p3) special slot map: msg k-layout is [x1(0..127) | msgE row at kt4:
// j0..2 = pos_s (unused -> 0), j3..5 = rel -> W rows 128..130].
__global__ __launch_bounds__(256) void pack_weights(
    const float* __restrict__ c1W1, const float* __restrict__ c1W2,
    const float* __restrict__ c2W1, const float* __restrict__ c2W2,
    __bf16* __restrict__ p1, __bf16* __restrict__ p2,
    __bf16* __restrict__ p3, __bf16* __restrict__ p4,
    unsigned int* __restrict__ pooled, __bf16* __restrict__ msgE)
{
    int t = blockIdx.x * 256 + threadIdx.x;
    if (t < GRAPHS * 256) pooled[t] = 0u;             // flipped(-inf) == 0
    if (t == 0) {
        bf16x8 z;
        #pragma unroll
        for (int j = 0; j < 8; j++) z[j] = (__bf16)0.f;
        *(bf16x8*)&msgE[(size_t)ZROW * 8] = z;
    }
    if (t >= 15872) return;
    const float* W; __bf16* out; int M, Kreal, KT, grp; bool c2w1 = false;
    if      (t <  512)  { W = c1W1; out = p1; M = 128; Kreal =   6; KT = 1; grp = t; }
    else if (t < 2560)  { W = c1W2; out = p2; M = 128; Kreal = 128; KT = 4; grp = t - 512; }
    else if (t < 7680)  { W = c2W1; out = p3; M = 256; Kreal = 131; KT = 5; grp = t - 2560; c2w1 = true; }
    else                { W = c2W2; out = p4; M = 256; Kreal = 256; KT = 8; grp = t - 7680; }
    int lane = grp & 63, rest = grp >> 6;
    int kt = rest % KT, mt = rest / KT;
    int m = mt * 16 + (lane & 15);
    int kbase = kt * 32 + ((lane >> 4) << 3);
    bf16x8 v;
    #pragma unroll
    for (int j = 0; j < 8; j++) {
        int ks = kbase + j;
        int wr;
        if (c2w1) wr = (ks < 128) ? ks : ((ks >= 131 && ks < 134) ? ks - 3 : -1);
        else      wr = (ks < Kreal) ? ks : -1;
        v[j] = (wr >= 0) ? (__bf16)W[wr * M + m] : (__bf16)0.f;
    }
    *(bf16x8*)&out[grp * 8] = v;
}

// =================== gatherE: edge message precompute (320k threads) ===========
__global__ __launch_bounds__(256) void gatherE_kernel(
    const float* __restrict__ pos, const int* __restrict__ esrc,
    __bf16* __restrict__ msgE)
{
    int e = blockIdx.x * 256 + threadIdx.x;          // < 320000
    int d = e >> 4;
    int s = esrc[e];
    float sx = pos[3*s], sy = pos[3*s+1], sz = pos[3*s+2];
    float dx = pos[3*d], dy = pos[3*d+1], dz = pos[3*d+2];
    bf16x8 v;
    v[0] = (__bf16)sx; v[1] = (__bf16)sy; v[2] = (__bf16)sz;
    v[3] = (__bf16)(sx - dx); v[4] = (__bf16)(sy - dy); v[5] = (__bf16)(sz - dz);
    v[6] = (__bf16)0.f; v[7] = (__bf16)0.f;
    *(bf16x8*)&msgE[(size_t)e * 8] = v;
}

// =================== conv1 v2: conv2's pipeline recipe ===================
// 500 blocks x 512 thr x 40 nodes (NT1=10 tiles of NB1T=4). Producers (waves
// 0-3): A1[2] resident; msgF triple-buffered via async16 from msgE (addresses
// purely linear -> coalesced, zero dep chain); vmcnt(2) guard; lgkm barriers.
// Consumers (waves 4-7): W2 frags resident, D[edge][ch], edge-max, x1 store.
#define NB1T 4
#define NT1 10
__global__ __launch_bounds__(512, 4) void conv1_kernel(
    const __bf16* __restrict__ msgE,
    const __bf16* __restrict__ W1p, const float* __restrict__ b1,
    const __bf16* __restrict__ W2p, const float* __restrict__ b2,
    __bf16* __restrict__ x1)
{
    __shared__ __attribute__((aligned(16))) __bf16 msgF[3][NB1T * 64 * 8];      // 3x4 KB
    __shared__ __attribute__((aligned(16))) __bf16 hidF[2][NB1T * 4 * 64 * 8];  // 2x16 KB
    const int tid = threadIdx.x, lane = tid & 63, wave = tid >> 6;
    const int quad = lane >> 4, col = lane & 15;
    const int base = blockIdx.x * (NB1T * NT1);

    if (wave < 4) {
        bf16x8 A1[2];
        f32x4 bias1[2];
        #pragma unroll
        for (int i = 0; i < 2; i++) {
            int mtg = wave * 2 + i;
            A1[i] = *(const bf16x8*)&W1p[(mtg * 64 + lane) * 8];
            bias1[i] = *(const f32x4*)&b1[mtg * 16 + quad * 4];
        }
        // stage tile td: wave stages node nl==wave (one async16 per wave)
        auto stage = [&](int td, int buf) {
            int nl = wave;
            int row = (quad == 0) ? ((base + td * NB1T + nl) * 16 + col) : ZROW;
            async16(&msgF[buf][nl * 64 * 8], &msgE[(size_t)row * 8]);
        };
        stage(0, 0);
        stage(1, 1);
        for (int k = 0; k < NT1; k++) {
            int td = k + 2; if (td >= NT1) td -= NT1;    // dummy tail keeps count uniform
            stage(td, (k + 2) % 3);
            __asm__ volatile("s_waitcnt vmcnt(2)" ::: "memory");
            const int bufi = k % 3, bufo = k & 1;
            #pragma unroll
            for (int nl = 0; nl < NB1T; nl++) {
                bf16x8 B = *(const bf16x8*)&msgF[bufi][(nl * 64 + lane) * 8];
                #pragma unroll
                for (int i = 0; i < 2; i++) {
                    int mtg = wave * 2 + i;
                    f32x4 acc = bias1[i];
                    acc = MFMA16(A1[i], B, acc);
                    union { __bf16 h[4]; uint2 u; } pk;
                    #pragma unroll
                    for (int r = 0; r < 4; r++) pk.h[r] = (__bf16)fmaxf(acc[r], 0.f);
                    int kt2 = mtg >> 1;
                    int lane2 = ((mtg * 2 + (quad >> 1)) & 3) * 16 + col;
                    int j0 = (quad & 1) * 4;
                    *(uint2*)&hidF[bufo][((nl * 4 + kt2) * 64 + lane2) * 8 + j0] = pk.u;
                }
            }
            ldsbar();
        }
    } else {
        const int wv = wave - 4;
        bf16x8 B2w[2][4];
        float b2v[2];
        #pragma unroll
        for (int i = 0; i < 2; i++) {
            int mtg = wv * 2 + i;
            #pragma unroll
            for (int kt = 0; kt < 4; kt++)
                B2w[i][kt] = *(const bf16x8*)&W2p[((mtg * 4 + kt) * 64 + lane) * 8];
            b2v[i] = b2[mtg * 16 + col];
        }
        for (int k = 0; k < NT1; k++) {
            ldsbar();                      // hidF[k&1] ready
            const int buf = k & 1;
            const int n0 = base + k * NB1T;
            #pragma unroll
            for (int nl = 0; nl < NB1T; nl++) {
                bf16x8 hA[4];
                #pragma unroll
                for (int kt = 0; kt < 4; kt++)
                    hA[kt] = *(const bf16x8*)&hidF[buf][((nl * 4 + kt) * 64 + lane) * 8];
                f32x4 acc[2];
                f32x4 z = {0.f, 0.f, 0.f, 0.f};
                acc[0] = z; acc[1] = z;
                #pragma unroll
                for (int kt = 0; kt < 4; kt++) {
                    #pragma unroll
                    for (int i = 0; i < 2; i++) acc[i] = MFMA16(hA[kt], B2w[i][kt], acc[i]);
                }
                #pragma unroll
                for (int i = 0; i < 2; i++) {
                    float m = fmaxf(fmaxf(acc[i][0], acc[i][1]), fmaxf(acc[i][2], acc[i][3]));
                    m = fmaxf(m, __shfl_xor(m, 16));
                    m = fmaxf(m, __shfl_xor(m, 32));
                    if (lane < 16)
                        x1[(size_t)(n0 + nl) * 128 + (wv * 2 + i) * 16 + lane] =
                            (__bf16)(m + b2v[i]);
                }
            }
        }
    }
}

// =================== conv2 =================== (R12 structure; relE -> msgE)
#define NB2 2
#define NT2 20
__global__ __launch_bounds__(512) __attribute__((amdgpu_waves_per_eu(2, 2)))
void conv2_kernel(
    const int* __restrict__ esrc,
    const __bf16* __restrict__ x1, const __bf16* __restrict__ msgE,
    const __bf16* __restrict__ W1p, const float* __restrict__ b1,
    const __bf16* __restrict__ W2p, const float* __restrict__ b2,
    unsigned int* __restrict__ pooled)
{
    __shared__ __attribute__((aligned(16))) __bf16 msgF[3][NB2 * 5 * 64 * 8];  // 3x10 KB
    __shared__ __attribute__((aligned(16))) __bf16 hidF[2][NB2 * 8 * 64 * 8];  // 2x16 KB
    __shared__ int sSrc[NB2 * NT2 * 16];                                       // 2.56 KB
    const int tid = threadIdx.x, lane = tid & 63, wave = tid >> 6;
    const int quad = lane >> 4, col = lane & 15;
    const int base = blockIdx.x * (NB2 * NT2);

    for (int u = tid; u < NB2 * NT2 * 16; u += 512) sSrc[u] = esrc[base * 16 + u];
    __syncthreads();

    if (wave < 4) {
        bf16x8 A1[4][5];
        f32x4 bias1[4];
        #pragma unroll
        for (int i = 0; i < 4; i++) {
            int tg = wave * 4 + i;
            #pragma unroll
            for (int kt = 0; kt < 5; kt++)
                A1[i][kt] = *(const bf16x8*)&W1p[((tg * 5 + kt) * 64 + lane) * 8];
            bias1[i] = *(const f32x4*)&b1[tg * 16 + quad * 4];
        }

        auto stage = [&](int td, int buf) {
            #pragma unroll
            for (int s = 0; s < 3; s++) {
                int g = wave + 4 * s;
                if (g < 10) {
                    int nl = g / 5, kt = g % 5;
                    __bf16* ldst = &msgF[buf][g * 64 * 8];
                    const __bf16* gsrc;
                    if (kt < 4) {
                        int src = sSrc[(td * NB2 + nl) * 16 + col];
                        gsrc = &x1[(size_t)src * 128 + kt * 32 + quad * 8];
                    } else {
                        int row = (quad == 0) ? ((base + td * NB2 + nl) * 16 + col) : ZROW;
                        gsrc = &msgE[(size_t)row * 8];
                    }
                    async16(ldst, gsrc);
                }
            }
        };

        stage(0, 0);
        stage(1, 1);

        for (int k = 0; k < NT2; k++) {
            int td = k + 2;
            if (td >= NT2) td -= NT2;
            stage(td, (k + 2) % 3);
            if (wave < 2) __asm__ volatile("s_waitcnt vmcnt(6)" ::: "memory");
            else          __asm__ volatile("s_waitcnt vmcnt(4)" ::: "memory");
            const int bufi = k % 3, bufo = k & 1;
            #pragma unroll
            for (int nl = 0; nl < NB2; nl++) {
                bf16x8 B[5];
                #pragma unroll
                for (int kt = 0; kt < 5; kt++)
                    B[kt] = *(const bf16x8*)&msgF[bufi][((nl * 5 + kt) * 64 + lane) * 8];
                #pragma unroll
                for (int i = 0; i < 4; i++) {
                    int mtg = wave * 4 + i;
                    f32x4 acc = bias1[i];
                    #pragma unroll
                    for (int kt = 0; kt < 5; kt++) acc = MFMA16(A1[i][kt], B[kt], acc);
                    union { __bf16 h[4]; uint2 u; } pk;
                    #pragma unroll
                    for (int r = 0; r < 4; r++) pk.h[r] = (__bf16)fmaxf(acc[r], 0.f);
                    int kt2 = mtg >> 1;
                    int lane2 = ((mtg * 2 + (quad >> 1)) & 3) * 16 + col;
                    int j0 = (quad & 1) * 4;
                    *(uint2*)&hidF[bufo][((nl * 8 + kt2) * 64 + lane2) * 8 + j0] = pk.u;
                }
            }
            ldsbar();
        }
    } else {
        const int wv = wave - 4;
        bf16x8 B2r[4][8];
        #pragma unroll
        for (int i = 0; i < 4; i++) {
            int tg = wv * 4 + i;
            #pragma unroll
            for (int kt = 0; kt < 8; kt++)
                B2r[i][kt] = *(const bf16x8*)&W2p[((tg * 8 + kt) * 64 + lane) * 8];
        }
        f32x4 runmax[4];
        #pragma unroll
        for (int i = 0; i < 4; i++)
            #pragma unroll
            for (int r = 0; r < 4; r++) runmax[i][r] = -3.4e38f;
        int gprev = base / NPG;

        auto flushfn = [&]() {
            #pragma unroll
            for (int i = 0; i < 4; i++) {
                float v = fmaxf(fmaxf(runmax[i][0], runmax[i][1]),
                                fmaxf(runmax[i][2], runmax[i][3]));
                v = fmaxf(v, __shfl_xor(v, 16));
                v = fmaxf(v, __shfl_xor(v, 32));
                if (lane < 16) {
                    int c = (wv * 4 + i) * 16 + lane;
                    float val = v + b2[c];
                    unsigned u = __float_as_uint(val);
                    u = (u & 0x80000000u) ? ~u : (u | 0x80000000u);
                    atomicMax(&pooled[gprev * 256 + c], u);
                }
                #pragma unroll
                for (int r = 0; r < 4; r++) runmax[i][r] = -3.4e38f;
            }
        };
        auto consume = [&](int tk) {
            int buf1 = tk & 1;
            int n0 = base + tk * NB2;
            #pragma unroll
            for (int nl = 0; nl < NB2; nl++) {
                int g = (n0 + nl) / NPG;
                if (g != gprev) { flushfn(); gprev = g; }
                bf16x8 hA[8];
                #pragma unroll
                for (int kt = 0; kt < 8; kt++)
                    hA[kt] = *(const bf16x8*)&hidF[buf1][((nl * 8 + kt) * 64 + lane) * 8];
                f32x4 acc[4];
                f32x4 z = {0.f, 0.f, 0.f, 0.f};
                #pragma unroll
                for (int i = 0; i < 4; i++) acc[i] = z;
                #pragma unroll
                for (int kt = 0; kt < 8; kt++) {
                    #pragma unroll
                    for (int i = 0; i < 4; i++) acc[i] = MFMA16(hA[kt], B2r[i][kt], acc[i]);
                }
                #pragma unroll
                for (int i = 0; i < 4; i++)
                    #pragma unroll
                    for (int r = 0; r < 4; r++)
                        runmax[i][r] = fmaxf(runmax[i][r], acc[i][r]);
            }
        };

        for (int k = 0; k < NT2; k++) {
            ldsbar();
            consume(k);
        }
        flushfn();
    }
}

// =================== head: fused, 16 blocks x 1024, 4-way k-split ===========
__global__ __launch_bounds__(1024) void head_kernel(
    const unsigned int* __restrict__ pooled,
    const float* __restrict__ fc1_W, const float* __restrict__ fc1_b,
    const float* __restrict__ fc2_W, const float* __restrict__ fc2_b,
    const float* __restrict__ lab_W, const float* __restrict__ lab_b,
    const float* __restrict__ box_W, const float* __restrict__ box_b,
    float* __restrict__ out)
{
    __shared__ float p[256], h1s[256], h2s[128], red[1024];
    const int g = blockIdx.x, tid = threadIdx.x;
    if (tid < 256) {
        unsigned u = pooled[g * 256 + tid];
        u = (u & 0x80000000u) ? (u & 0x7fffffffu) : ~u;
        p[tid] = __uint_as_float(u);
    }
    __syncthreads();
    {   // fc1: c = tid&255, k-quarter = tid>>8
        int c = tid & 255, kq = tid >> 8;
        float a = 0.f;
        #pragma unroll 8
        for (int k0 = 0; k0 < 64; k0++) {
            int k = kq * 64 + k0;
            a += p[k] * fc1_W[k * 256 + c];
        }
        red[tid] = a;
    }
    __syncthreads();
    if (tid < 256)
        h1s[tid] = fmaxf(red[tid] + red[256 + tid] + red[512 + tid] + red[768 + tid]
                         + fc1_b[tid], 0.f);
    __syncthreads();
    if (tid < 512) {    // fc2: c = tid&127, k-quarter = tid>>7
        int c = tid & 127, kq = tid >> 7;
        float a = 0.f;
        #pragma unroll 8
        for (int k0 = 0; k0 < 64; k0++) {
            int k = kq * 64 + k0;
            a += h1s[k] * fc2_W[k * 128 + c];
        }
        red[tid] = a;
    }
    __syncthreads();
    if (tid < 128)
        h2s[tid] = fmaxf(red[tid] + red[128 + tid] + red[256 + tid] + red[384 + tid]
                         + fc2_b[tid], 0.f);
    __syncthreads();
    if (tid < 128) {    // lab+box: o = tid>>3 (0..15), k-eighth = tid&7
        int o = tid >> 3, kq = tid & 7;
        float a = 0.f;
        #pragma unroll
        for (int k0 = 0; k0 < 16; k0++) {
            int k = kq * 16 + k0;
            float w = (o < 10) ? lab_W[k * 10 + o] : box_W[k * 6 + (o - 10)];
            a += h2s[k] * w;
        }
        red[tid] = a;
    }
    __syncthreads();
    if (tid < 16) {
        float a = 0.f;
        #pragma unroll
        for (int q = 0; q < 8; q++) a += red[tid * 8 + q];
        if (tid < 10) out[g * 10 + tid] = a + lab_b[tid];
        else          out[160 + g * 6 + (tid - 10)] = a + box_b[tid - 10];
    }
}

extern "C" void kernel_launch(void* const* d_in, const int* in_sizes, int n_in,
                              void* d_out, int out_size, void* d_ws, size_t ws_size,
                              hipStream_t stream) {
    const float* pos   = (const float*)d_in[0];
    const int*   esrc  = (const int*)  d_in[1];
    const float* c1W1 = (const float*)d_in[4];
    const float* c1b1 = (const float*)d_in[5];
    const float* c1W2 = (const float*)d_in[6];
    const float* c1b2 = (const float*)d_in[7];
    const float* c2W1 = (const float*)d_in[8];
    const float* c2b1 = (const float*)d_in[9];
    const float* c2W2 = (const float*)d_in[10];
    const float* c2b2 = (const float*)d_in[11];
    const float* fc1W = (const float*)d_in[12];
    const float* fc1b = (const float*)d_in[13];
    const float* fc2W = (const float*)d_in[14];
    const float* fc2b = (const float*)d_in[15];
    const float* labW = (const float*)d_in[16];
    const float* labb = (const float*)d_in[17];
    const float* boxW = (const float*)d_in[18];
    const float* boxb = (const float*)d_in[19];

    __bf16* wsb = (__bf16*)d_ws;
    __bf16* x1   = wsb + OFF_X1;
    __bf16* p1   = wsb + OFF_P1;
    __bf16* p2   = wsb + OFF_P2;
    __bf16* p3   = wsb + OFF_P3;
    __bf16* p4   = wsb + OFF_P4;
    __bf16* msgE = wsb + OFF_MSGE;
    unsigned int* pooled = (unsigned int*)((char*)d_ws + OFF_POOL_BYTES);

    pack_weights<<<62, 256, 0, stream>>>(c1W1, c1W2, c2W1, c2W2, p1, p2, p3, p4, pooled, msgE);
    gatherE_kernel<<<1250, 256, 0, stream>>>(pos, esrc, msgE);
    conv1_kernel<<<N_NODES / (NB1T * NT1), 512, 0, stream>>>(msgE, p1, c1b1, p2, c1b2, x1);
    conv2_kernel<<<N_NODES / (NB2 * NT2), 512, 0, stream>>>(esrc, x1, msgE, p3, c2b1, p4, c2b2, pooled);
    head_kernel<<<GRAPHS, 1024, 0, stream>>>(pooled, fc1W, fc1b, fc2W, fc2b,
                                             labW, labb, boxW, boxb, (float*)d_out);
}

// Round 15
// 182.912 us; speedup vs baseline: 1.3024x; 1.0518x over previous
//
#include <hip/hip_runtime.h>

#define N_NODES 20000
#define DEG 16
#define GRAPHS 16
#define NPG 1250

typedef __bf16 bf16x8 __attribute__((ext_vector_type(8)));
typedef float f32x4 __attribute__((ext_vector_type(4)));
#define MFMA16(a, b, c) __builtin_amdgcn_mfma_f32_16x16x32_bf16(a, b, c, 0, 0, 0)

// LDS-only barrier: waits LDS ops, does NOT drain vmcnt.
__device__ __forceinline__ void ldsbar() {
    __asm__ volatile("s_waitcnt lgkmcnt(0)\n\ts_barrier" ::: "memory");
}
// async global->LDS direct copy, 16 B per lane; LDS dest = uniform base + lane*16
__device__ __forceinline__ void async16(void* lds, const void* g) {
    __builtin_amdgcn_global_load_lds(
        (const __attribute__((address_space(1))) unsigned int*)(g),
        (__attribute__((address_space(3))) unsigned int*)(lds), 16, 0, 0);
}

// ---- workspace layout ----
#define OFF_X1    0            // x1 [20000][128] bf16
#define OFF_P1    2560000      // c1W1 packed: MT=8  KT=1 -> 4096
#define OFF_P2    2564096      // c1W2 packed: MT=8  KT=4 -> 16384
#define OFF_P3    2580480      // c2W1 packed: MT=16 KT=5 -> 40960
#define OFF_P4    2621440      // c2W2 packed: MT=16 KT=8 -> 65536
#define OFF_POOL_BYTES 5373952 // pooled u32[16*256]
#define OFF_MSGE  2695176      // msgE (bf16 elems): row e = [sx,sy,sz,rx,ry,rz,0,0]
#define ZROW      320000       //   row 320000 = zeros

// =================== prep: pack weights + pooled init + edge messages =========
// grid 1250 x 256 = 320000 threads (exactly E).
__global__ __launch_bounds__(256) void prep_kernel(
    const float* __restrict__ pos, const int* __restrict__ esrc,
    const float* __restrict__ c1W1, const float* __restrict__ c1W2,
    const float* __restrict__ c2W1, const float* __restrict__ c2W2,
    __bf16* __restrict__ p1, __bf16* __restrict__ p2,
    __bf16* __restrict__ p3, __bf16* __restrict__ p4,
    unsigned int* __restrict__ pooled, __bf16* __restrict__ msgE)
{
    int t = blockIdx.x * 256 + threadIdx.x;
    {   // gatherE: one edge per thread
        int e = t, d = e >> 4;
        int s = esrc[e];
        float sx = pos[3*s], sy = pos[3*s+1], sz = pos[3*s+2];
        float dx = pos[3*d], dy = pos[3*d+1], dz = pos[3*d+2];
        bf16x8 v;
        v[0] = (__bf16)sx; v[1] = (__bf16)sy; v[2] = (__bf16)sz;
        v[3] = (__bf16)(sx - dx); v[4] = (__bf16)(sy - dy); v[5] = (__bf16)(sz - dz);
        v[6] = (__bf16)0.f; v[7] = (__bf16)0.f;
        *(bf16x8*)&msgE[(size_t)e * 8] = v;
    }
    if (t < GRAPHS * 256) pooled[t] = 0u;             // flipped(-inf) == 0
    if (t == 0) {
        bf16x8 z;
        #pragma unroll
        for (int j = 0; j < 8; j++) z[j] = (__bf16)0.f;
        *(bf16x8*)&msgE[(size_t)ZROW * 8] = z;
    }
    if (t >= 15872) return;
    const float* W; __bf16* out; int M, Kreal, KT, grp; bool c2w1 = false;
    if      (t <  512)  { W = c1W1; out = p1; M = 128; Kreal =   6; KT = 1; grp = t; }
    else if (t < 2560)  { W = c1W2; out = p2; M = 128; Kreal = 128; KT = 4; grp = t - 512; }
    else if (t < 7680)  { W = c2W1; out = p3; M = 256; Kreal = 131; KT = 5; grp = t - 2560; c2w1 = true; }
    else                { W = c2W2; out = p4; M = 256; Kreal = 256; KT = 8; grp = t - 7680; }
    int lane = grp & 63, rest = grp >> 6;
    int kt = rest % KT, mt = rest / KT;
    int m = mt * 16 + (lane & 15);
    int kbase = kt * 32 + ((lane >> 4) << 3);
    bf16x8 v;
    #pragma unroll
    for (int j = 0; j < 8; j++) {
        int ks = kbase + j;
        int wr;
        if (c2w1) wr = (ks < 128) ? ks : ((ks >= 131 && ks < 134) ? ks - 3 : -1);
        else      wr = (ks < Kreal) ? ks : -1;
        v[j] = (wr >= 0) ? (__bf16)W[wr * M + m] : (__bf16)0.f;
    }
    *(bf16x8*)&out[grp * 8] = v;
}

// =================== conv1 v3: 16 nodes per barrier interval ===================
// 250 blocks x 512 thr x 80 nodes (NT1=5 tiles of NB1T=16). UNIFIED waves: each
// of the 8 waves owns 1 of 8 channel-tiles in BOTH layers. msgF triple-buffered
// DMA from msgE (linear addresses, 2 async16/wave/tile, vmcnt(4)); hidF single
// 64KB; 2 lgkm-only barriers per 16-node tile (10 intervals/CU total vs R14's 40).
#define NB1T 16
#define NT1 5
__global__ __launch_bounds__(512, 2) void conv1_kernel(
    const __bf16* __restrict__ msgE,
    const __bf16* __restrict__ W1p, const float* __restrict__ b1,
    const __bf16* __restrict__ W2p, const float* __restrict__ b2,
    __bf16* __restrict__ x1)
{
    __shared__ __attribute__((aligned(16))) __bf16 msgF[3][NB1T * 64 * 8];   // 3x16 KB
    __shared__ __attribute__((aligned(16))) __bf16 hidF[NB1T * 4 * 64 * 8];  // 64 KB
    const int tid = threadIdx.x, lane = tid & 63, wave = tid >> 6;
    const int quad = lane >> 4, col = lane & 15;
    const int base = blockIdx.x * (NB1T * NT1);

    // resident: layer1 A-frag (mtile = wave), layer2 B-frags (ch-tile = wave)
    bf16x8 A1 = *(const bf16x8*)&W1p[(wave * 64 + lane) * 8];
    f32x4 bias1 = *(const f32x4*)&b1[wave * 16 + quad * 4];
    bf16x8 B2w[4];
    #pragma unroll
    for (int kt = 0; kt < 4; kt++)
        B2w[kt] = *(const bf16x8*)&W2p[((wave * 4 + kt) * 64 + lane) * 8];
    float b2v = b2[wave * 16 + col];

    auto stage = [&](int td, int buf) {     // wave stages nodes {2w, 2w+1}
        #pragma unroll
        for (int s = 0; s < 2; s++) {
            int nl = wave * 2 + s;
            int row = (quad == 0) ? ((base + td * NB1T + nl) * 16 + col) : ZROW;
            async16(&msgF[buf][nl * 64 * 8], &msgE[(size_t)row * 8]);
        }
    };
    stage(0, 0);
    stage(1, 1);

    for (int k = 0; k < NT1; k++) {
        int td = k + 2; if (td >= NT1) td -= NT1;   // dummy tail keeps count uniform
        stage(td, (k + 2) % 3);
        __asm__ volatile("s_waitcnt vmcnt(4)" ::: "memory");  // tile-k DMAs done
        const int bufi = k % 3;
        // phase 1: D[ch][edge] for my mtile, all 16 nodes -> hidF
        #pragma unroll
        for (int nl = 0; nl < NB1T; nl++) {
            bf16x8 B = *(const bf16x8*)&msgF[bufi][(nl * 64 + lane) * 8];
            f32x4 acc = bias1;
            acc = MFMA16(A1, B, acc);
            union { __bf16 h[4]; uint2 u; } pk;
            #pragma unroll
            for (int r = 0; r < 4; r++) pk.h[r] = (__bf16)fmaxf(acc[r], 0.f);
            int kt2 = wave >> 1;
            int lane2 = ((wave * 2 + (quad >> 1)) & 3) * 16 + col;
            int j0 = (quad & 1) * 4;
            *(uint2*)&hidF[((nl * 4 + kt2) * 64 + lane2) * 8 + j0] = pk.u;
        }
        ldsbar();                                   // hidF ready
        // phase 2: D[edge][ch] for my ch-tile, edge-max, store x1
        const int n0 = base + k * NB1T;
        #pragma unroll
        for (int nl = 0; nl < NB1T; nl++) {
            bf16x8 hA[4];
            #pragma unroll
            for (int kt = 0; kt < 4; kt++)
                hA[kt] = *(const bf16x8*)&hidF[((nl * 4 + kt) * 64 + lane) * 8];
            f32x4 acc = {0.f, 0.f, 0.f, 0.f};
            #pragma unroll
            for (int kt = 0; kt < 4; kt++) acc = MFMA16(hA[kt], B2w[kt], acc);
            float m = fmaxf(fmaxf(acc[0], acc[1]), fmaxf(acc[2], acc[3]));
            m = fmaxf(m, __shfl_xor(m, 16));
            m = fmaxf(m, __shfl_xor(m, 32));
            if (lane < 16)
                x1[(size_t)(n0 + nl) * 128 + wave * 16 + lane] = (__bf16)(m + b2v);
        }
        ldsbar();                                   // hidF free for next tile
    }
}

// =================== conv2: NB2=4 (half the barrier intervals) ===================
// 250 blocks x 512 thr x 80 nodes (NT2=20 tiles of NB2=4). Producers (waves 0-3,
// A1 resident), consumers (waves 4-7, W2 resident). msgF triple-buffered DMA,
// uniform 5 async16/wave/tile -> vmcnt(10); lgkm-only barriers. LDS ~129 KB,
// 1 block/CU (which waves_per_eu(2,2) forces anyway).
#define NB2 4
#define NT2 20
__global__ __launch_bounds__(512) __attribute__((amdgpu_waves_per_eu(2, 2)))
void conv2_kernel(
    const int* __restrict__ esrc,
    const __bf16* __restrict__ x1, const __bf16* __restrict__ msgE,
    const __bf16* __restrict__ W1p, const float* __restrict__ b1,
    const __bf16* __restrict__ W2p, const float* __restrict__ b2,
    unsigned int* __restrict__ pooled)
{
    __shared__ __attribute__((aligned(16))) __bf16 msgF[3][NB2 * 5 * 64 * 8];  // 3x20 KB
    __shared__ __attribute__((aligned(16))) __bf16 hidF[2][NB2 * 8 * 64 * 8];  // 2x32 KB
    __shared__ int sSrc[NB2 * NT2 * 16];                                       // 5.1 KB
    const int tid = threadIdx.x, lane = tid & 63, wave = tid >> 6;
    const int quad = lane >> 4, col = lane & 15;
    const int base = blockIdx.x * (NB2 * NT2);

    for (int u = tid; u < NB2 * NT2 * 16; u += 512) sSrc[u] = esrc[base * 16 + u];
    __syncthreads();

    if (wave < 4) {
        bf16x8 A1[4][5];
        f32x4 bias1[4];
        #pragma unroll
        for (int i = 0; i < 4; i++) {
            int tg = wave * 4 + i;
            #pragma unroll
            for (int kt = 0; kt < 5; kt++)
                A1[i][kt] = *(const bf16x8*)&W1p[((tg * 5 + kt) * 64 + lane) * 8];
            bias1[i] = *(const f32x4*)&b1[tg * 16 + quad * 4];
        }

        auto stage = [&](int td, int buf) {        // 20 groups / 4 waves = 5 each
            #pragma unroll
            for (int s = 0; s < 5; s++) {
                int g = wave + 4 * s;
                int nl = g / 5, kt = g % 5;
                __bf16* ldst = &msgF[buf][g * 64 * 8];
                const __bf16* gsrc;
                if (kt < 4) {
                    int src = sSrc[(td * NB2 + nl) * 16 + col];
                    gsrc = &x1[(size_t)src * 128 + kt * 32 + quad * 8];
                } else {
                    int row = (quad == 0) ? ((base + td * NB2 + nl) * 16 + col) : ZROW;
                    gsrc = &msgE[(size_t)row * 8];
                }
                async16(ldst, gsrc);
            }
        };

        stage(0, 0);
        stage(1, 1);

        for (int k = 0; k < NT2; k++) {
            int td = k + 2;
            if (td >= NT2) td -= NT2;
            stage(td, (k + 2) % 3);
            __asm__ volatile("s_waitcnt vmcnt(10)" ::: "memory");  // tile-k done
            const int bufi = k % 3, bufo = k & 1;
            #pragma unroll
            for (int nl = 0; nl < NB2; nl++) {
                bf16x8 B[5];
                #pragma unroll
                for (int kt = 0; kt < 5; kt++)
                    B[kt] = *(const bf16x8*)&msgF[bufi][((nl * 5 + kt) * 64 + lane) * 8];
                #pragma unroll
                for (int i = 0; i < 4; i++) {
                    int mtg = wave * 4 + i;
                    f32x4 acc = bias1[i];
                    #pragma unroll
                    for (int kt = 0; kt < 5; kt++) acc = MFMA16(A1[i][kt], B[kt], acc);
                    union { __bf16 h[4]; uint2 u; } pk;
                    #pragma unroll
                    for (int r = 0; r < 4; r++) pk.h[r] = (__bf16)fmaxf(acc[r], 0.f);
                    int kt2 = mtg >> 1;
                    int lane2 = ((mtg * 2 + (quad >> 1)) & 3) * 16 + col;
                    int j0 = (quad & 1) * 4;
                    *(uint2*)&hidF[bufo][((nl * 8 + kt2) * 64 + lane2) * 8 + j0] = pk.u;
                }
            }
            ldsbar();
        }
    } else {
        const int wv = wave - 4;
        bf16x8 B2r[4][8];
        #pragma unroll
        for (int i = 0; i < 4; i++) {
            int tg = wv * 4 + i;
            #pragma unroll
            for (int kt = 0; kt < 8; kt++)
                B2r[i][kt] = *(const bf16x8*)&W2p[((tg * 8 + kt) * 64 + lane) * 8];
        }
        f32x4 runmax[4];
        #pragma unroll
        for (int i = 0; i < 4; i++)
            #pragma unroll
            for (int r = 0; r < 4; r++) runmax[i][r] = -3.4e38f;
        int gprev = base / NPG;

        auto flushfn = [&]() {
            #pragma unroll
            for (int i = 0; i < 4; i++) {
                float v = fmaxf(fmaxf(runmax[i][0], runmax[i][1]),
                                fmaxf(runmax[i][2], runmax[i][3]));
                v = fmaxf(v, __shfl_xor(v, 16));
                v = fmaxf(v, __shfl_xor(v, 32));
                if (lane < 16) {
                    int c = (wv * 4 + i) * 16 + lane;
                    float val = v + b2[c];
                    unsigned u = __float_as_uint(val);
                    u = (u & 0x80000000u) ? ~u : (u | 0x80000000u);
                    atomicMax(&pooled[gprev * 256 + c], u);
                }
                #pragma unroll
                for (int r = 0; r < 4; r++) runmax[i][r] = -3.4e38f;
            }
        };
        auto consume = [&](int tk) {
            int buf1 = tk & 1;
            int n0 = base + tk * NB2;
            #pragma unroll
            for (int nl = 0; nl < NB2; nl++) {
                int g = (n0 + nl) / NPG;
                if (g != gprev) { flushfn(); gprev = g; }
                bf16x8 hA[8];
                #pragma unroll
                for (int kt = 0; kt < 8; kt++)
                    hA[kt] = *(const bf16x8*)&hidF[buf1][((nl * 8 + kt) * 64 + lane) * 8];
                f32x4 acc[4];
                f32x4 z = {0.f, 0.f, 0.f, 0.f};
                #pragma unroll
                for (int i = 0; i < 4; i++) acc[i] = z;
                #pragma unroll
                for (int kt = 0; kt < 8; kt++) {
                    #pragma unroll
                    for (int i = 0; i < 4; i++) acc[i] = MFMA16(hA[kt], B2r[i][kt], acc[i]);
                }
                #pragma unroll
                for (int i = 0; i < 4; i++)
                    #pragma unroll
                    for (int r = 0; r < 4; r++)
                        runmax[i][r] = fmaxf(runmax[i][r], acc[i][r]);
            }
        };

        for (int k = 0; k < NT2; k++) {
            ldsbar();
            consume(k);
        }
        flushfn();
    }
}

// =================== head: fused, 16 blocks x 1024, 4-way k-split ===========
__global__ __launch_bounds__(1024) void head_kernel(
    const unsigned int* __restrict__ pooled,
    const float* __restrict__ fc1_W, const float* __restrict__ fc1_b,
    const float* __restrict__ fc2_W, const float* __restrict__ fc2_b,
    const float* __restrict__ lab_W, const float* __restrict__ lab_b,
    const float* __restrict__ box_W, const float* __restrict__ box_b,
    float* __restrict__ out)
{
    __shared__ float p[256], h1s[256], h2s[128], red[1024];
    const int g = blockIdx.x, tid = threadIdx.x;
    if (tid < 256) {
        unsigned u = pooled[g * 256 + tid];
        u = (u & 0x80000000u) ? (u & 0x7fffffffu) : ~u;
        p[tid] = __uint_as_float(u);
    }
    __syncthreads();
    {
        int c = tid & 255, kq = tid >> 8;
        float a = 0.f;
        #pragma unroll 8
        for (int k0 = 0; k0 < 64; k0++) {
            int k = kq * 64 + k0;
            a += p[k] * fc1_W[k * 256 + c];
        }
        red[tid] = a;
    }
    __syncthreads();
    if (tid < 256)
        h1s[tid] = fmaxf(red[tid] + red[256 + tid] + red[512 + tid] + red[768 + tid]
                         + fc1_b[tid], 0.f);
    __syncthreads();
    if (tid < 512) {
        int c = tid & 127, kq = tid >> 7;
        float a = 0.f;
        #pragma unroll 8
        for (int k0 = 0; k0 < 64; k0++) {
            int k = kq * 64 + k0;
            a += h1s[k] * fc2_W[k * 128 + c];
        }
        red[tid] = a;
    }
    __syncthreads();
    if (tid < 128)
        h2s[tid] = fmaxf(red[tid] + red[128 + tid] + red[256 + tid] + red[384 + tid]
                         + fc2_b[tid], 0.f);
    __syncthreads();
    if (tid < 128) {
        int o = tid >> 3, kq = tid & 7;
        float a = 0.f;
        #pragma unroll
        for (int k0 = 0; k0 < 16; k0++) {
            int k = kq * 16 + k0;
            float w = (o < 10) ? lab_W[k * 10 + o] : box_W[k * 6 + (o - 10)];
            a += h2s[k] * w;
        }
        red[tid] = a;
    }
    __syncthreads();
    if (tid < 16) {
        float a = 0.f;
        #pragma unroll
        for (int q = 0; q < 8; q++) a += red[tid * 8 + q];
        if (tid < 10) out[g * 10 + tid] = a + lab_b[tid];
        else          out[160 + g * 6 + (tid - 10)] = a + box_b[tid - 10];
    }
}

extern "C" void kernel_launch(void* const* d_in, const int* in_sizes, int n_in,
                              void* d_out, int out_size, void* d_ws, size_t ws_size,
                              hipStream_t stream) {
    const float* pos   = (const float*)d_in[0];
    const int*   esrc  = (const int*)  d_in[1];
    const float* c1W1 = (const float*)d_in[4];
    const float* c1b1 = (const float*)d_in[5];
    const float* c1W2 = (const float*)d_in[6];
    const float* c1b2 = (const float*)d_in[7];
    const float* c2W1 = (const float*)d_in[8];
    const float* c2b1 = (const float*)d_in[9];
    const float* c2W2 = (const float*)d_in[10];
    const float* c2b2 = (const float*)d_in[11];
    const float* fc1W = (const float*)d_in[12];
    const float* fc1b = (const float*)d_in[13];
    const float* fc2W = (const float*)d_in[14];
    const float* fc2b = (const float*)d_in[15];
    const float* labW = (const float*)d_in[16];
    const float* labb = (const float*)d_in[17];
    const float* boxW = (const float*)d_in[18];
    const float* boxb = (const float*)d_in[19];

    __bf16* wsb = (__bf16*)d_ws;
    __bf16* x1   = wsb + OFF_X1;
    __bf16* p1   = wsb + OFF_P1;
    __bf16* p2   = wsb + OFF_P2;
    __bf16* p3   = wsb + OFF_P3;
    __bf16* p4   = wsb + OFF_P4;
    __bf16* msgE = wsb + OFF_MSGE;
    unsigned int* pooled = (unsigned int*)((char*)d_ws + OFF_POOL_BYTES);

    prep_kernel<<<1250, 256, 0, stream>>>(pos, esrc, c1W1, c1W2, c2W1, c2W2,
                                          p1, p2, p3, p4, pooled, msgE);
    conv1_kernel<<<N_NODES / (NB1T * NT1), 512, 0, stream>>>(msgE, p1, c1b1, p2, c1b2, x1);
    conv2_kernel<<<N_NODES / (NB2 * NT2), 512, 0, stream>>>(esrc, x1, msgE, p3, c2b1, p4, c2b2, pooled);
    head_kernel<<<GRAPHS, 1024, 0, stream>>>(pooled, fc1W, fc1b, fc2W, fc2b,
                                             labW, labb, boxW, boxb, (float*)d_out);
}